// Round 1
// baseline (1964.619 us; speedup 1.0000x reference)
//
#include <hip/hip_runtime.h>
#include <math.h>

#define BB 2
#define NN 32768
#define KK 16
#define DD 256
#define AA 64
#define VV 64
#define R1 8   // rows per block in row-batched kernels

// ---------------- Kernel 1: LN1 + QKV projection (8 rows / block) ----------------
__global__ __launch_bounds__(256) void k_ln_qkv(
    const float* __restrict__ x, const float* __restrict__ g1, const float* __restrict__ b1,
    const float* __restrict__ Wq, const float* __restrict__ bq,
    const float* __restrict__ Wk, const float* __restrict__ bk,
    const float* __restrict__ Wv, const float* __restrict__ bv,
    float* __restrict__ qo, float* __restrict__ ko, float* __restrict__ vo) {
  __shared__ float hT[DD][R1];   // transposed: hT[d][r] -> 8 consecutive floats per d
  int t = threadIdx.x;
  int lane = t & 63, wid = t >> 6;
  size_t row0 = (size_t)blockIdx.x * R1;

  // phase 1: LayerNorm, wave w handles rows w and w+4
  for (int rr = 0; rr < 2; rr++) {
    int r = wid + rr * 4;
    size_t row = row0 + r;
    float xv[4]; float s = 0.f, s2 = 0.f;
    #pragma unroll
    for (int i = 0; i < 4; i++) {
      xv[i] = x[row * DD + lane + i * 64];
      s += xv[i]; s2 += xv[i] * xv[i];
    }
    for (int off = 32; off > 0; off >>= 1) {
      s  += __shfl_down(s, off, 64);
      s2 += __shfl_down(s2, off, 64);
    }
    s = __shfl(s, 0, 64); s2 = __shfl(s2, 0, 64);
    float m = s * (1.f / DD);
    float rs = rsqrtf(s2 * (1.f / DD) - m * m + 1e-5f);
    #pragma unroll
    for (int i = 0; i < 4; i++) {
      int d = lane + i * 64;
      hT[d][r] = (xv[i] - m) * rs * g1[d] + b1[d];
    }
  }
  __syncthreads();

  // phase 2: q/k/v matvec, 8 rows share each weight load
  if (t < 192) {
    int grp = t >> 6, a = t & 63;
    const float* W    = (grp == 0) ? Wq : (grp == 1) ? Wk : Wv;
    const float* bias = (grp == 0) ? bq : (grp == 1) ? bk : bv;
    float acc[R1];
    #pragma unroll
    for (int r = 0; r < R1; r++) acc[r] = bias[a];
    for (int d = 0; d < DD; d++) {
      float w = W[d * AA + a];
      #pragma unroll
      for (int r = 0; r < R1; r++) acc[r] += hT[d][r] * w;
    }
    float* out = (grp == 0) ? qo : (grp == 1) ? ko : vo;
    #pragma unroll
    for (int r = 0; r < R1; r++) out[(row0 + r) * AA + a] = acc[r];
  }
}

// ---------------- Kernel 2: per-point attention (one block per n, both batches) ----------------
__global__ __launch_bounds__(256) void k_attn(
    const float* __restrict__ x, const float* __restrict__ relpos, const int* __restrict__ knn,
    const float* __restrict__ qg, const float* __restrict__ kg, const float* __restrict__ vg,
    const float* __restrict__ Wpa1, const float* __restrict__ bpa1,
    const float* __restrict__ Wpa2, const float* __restrict__ bpa2,
    const float* __restrict__ Wpv1, const float* __restrict__ bpv1,
    const float* __restrict__ Wpv2, const float* __restrict__ bpv2,
    const float* __restrict__ Ws1, const float* __restrict__ bs1,
    const float* __restrict__ Ws2, const float* __restrict__ bs2,
    const float* __restrict__ Wo, const float* __restrict__ bo,
    float* __restrict__ xmid) {
  int n = blockIdx.x;
  int t = threadIdx.x;
  __shared__ float ra[KK][AA];
  __shared__ float rv[KK][VV];
  __shared__ float hid[KK][AA];   // scratch (rel-pos hidden, then score hidden)
  __shared__ float tl[KK][AA];
  __shared__ float qs[AA];
  __shared__ float ctx[VV];
  __shared__ float attn[KK];
  __shared__ float sc[KK];
  __shared__ int   idx[KK];

  if (t < KK) idx[t] = knn[n * KK + t];

  // rel-pos attn MLP hidden
  #pragma unroll
  for (int i = 0; i < 4; i++) {
    int p = t + i * 256; int k = p >> 6, a = p & 63;
    const float* rp = relpos + ((size_t)n * KK + k) * 3;
    float acc = bpa1[a] + rp[0] * Wpa1[0 * AA + a] + rp[1] * Wpa1[1 * AA + a] + rp[2] * Wpa1[2 * AA + a];
    hid[k][a] = fmaxf(acc, 0.f);
  }
  __syncthreads();
  #pragma unroll
  for (int i = 0; i < 4; i++) {
    int p = t + i * 256; int k = p >> 6, a = p & 63;
    float acc = bpa2[a];
    for (int a1 = 0; a1 < AA; a1++) acc += hid[k][a1] * Wpa2[a1 * AA + a];
    ra[k][a] = acc;
  }
  __syncthreads();
  // rel-pos value MLP hidden
  #pragma unroll
  for (int i = 0; i < 4; i++) {
    int p = t + i * 256; int k = p >> 6, a = p & 63;
    const float* rp = relpos + ((size_t)n * KK + k) * 3;
    float acc = bpv1[a] + rp[0] * Wpv1[0 * VV + a] + rp[1] * Wpv1[1 * VV + a] + rp[2] * Wpv1[2 * VV + a];
    hid[k][a] = fmaxf(acc, 0.f);
  }
  __syncthreads();
  #pragma unroll
  for (int i = 0; i < 4; i++) {
    int p = t + i * 256; int k = p >> 6, a = p & 63;
    float acc = bpv2[a];
    for (int a1 = 0; a1 < VV; a1++) acc += hid[k][a1] * Wpv2[a1 * VV + a];
    rv[k][a] = acc;
  }
  __syncthreads();

  for (int b = 0; b < BB; b++) {
    size_t rowbase = (size_t)b * NN + n;
    if (t < AA) qs[t] = qg[rowbase * AA + t];
    __syncthreads();
    // t = tanh(q - kn + ra)
    #pragma unroll
    for (int i = 0; i < 4; i++) {
      int p = t + i * 256; int k = p >> 6, a = p & 63;
      float kv = kg[((size_t)b * NN + idx[k]) * AA + a];
      tl[k][a] = tanhf(qs[a] - kv + ra[k][a]);
    }
    __syncthreads();
    // hidden = relu(t @ Ws1 + bs1)
    #pragma unroll
    for (int i = 0; i < 4; i++) {
      int p = t + i * 256; int k = p >> 6, a = p & 63;
      float acc = bs1[a];
      for (int a1 = 0; a1 < AA; a1++) acc += tl[k][a1] * Ws1[a1 * AA + a];
      hid[k][a] = fmaxf(acc, 0.f);
    }
    __syncthreads();
    // score
    if (t < KK) {
      float acc = bs2[0];
      for (int a1 = 0; a1 < AA; a1++) acc += hid[t][a1] * Ws2[a1];
      sc[t] = acc * 0.125f;   // / sqrt(64)
    }
    __syncthreads();
    if (t == 0) {
      float mx = sc[0];
      for (int k = 1; k < KK; k++) mx = fmaxf(mx, sc[k]);
      float ssum = 0.f;
      for (int k = 0; k < KK; k++) { float e = __expf(sc[k] - mx); attn[k] = e; ssum += e; }
      float inv = 1.f / ssum;
      for (int k = 0; k < KK; k++) attn[k] *= inv;
    }
    __syncthreads();
    // ctx = sum_k attn * (vn + rv)
    if (t < VV) {
      float acc = 0.f;
      for (int k = 0; k < KK; k++) {
        float vn = vg[((size_t)b * NN + idx[k]) * VV + t];
        acc += attn[k] * (vn + rv[k][t]);
      }
      ctx[t] = acc;
    }
    __syncthreads();
    // xmid = x + ctx @ Wo + bo
    {
      float acc = bo[t];
      for (int v = 0; v < VV; v++) acc += ctx[v] * Wo[v * DD + t];
      xmid[rowbase * DD + t] = x[rowbase * DD + t] + acc;
    }
    __syncthreads();
  }
}

// ---------------- Kernel 3: LN2 + FFN + residual (8 rows / block) ----------------
__global__ __launch_bounds__(256) void k_ffn(
    const float* __restrict__ xmid, const float* __restrict__ g2, const float* __restrict__ b2,
    const float* __restrict__ Wf1, const float* __restrict__ bf1,
    const float* __restrict__ Wf2, const float* __restrict__ bf2,
    float* __restrict__ out) {
  __shared__ float hT[DD][R1];       // 8 KB
  __shared__ float yT[2 * DD][R1];   // 16 KB
  int t = threadIdx.x;
  int lane = t & 63, wid = t >> 6;
  size_t row0 = (size_t)blockIdx.x * R1;

  for (int rr = 0; rr < 2; rr++) {
    int r = wid + rr * 4;
    size_t row = row0 + r;
    float xv[4]; float s = 0.f, s2 = 0.f;
    #pragma unroll
    for (int i = 0; i < 4; i++) {
      xv[i] = xmid[row * DD + lane + i * 64];
      s += xv[i]; s2 += xv[i] * xv[i];
    }
    for (int off = 32; off > 0; off >>= 1) {
      s  += __shfl_down(s, off, 64);
      s2 += __shfl_down(s2, off, 64);
    }
    s = __shfl(s, 0, 64); s2 = __shfl(s2, 0, 64);
    float m = s * (1.f / DD);
    float rs = rsqrtf(s2 * (1.f / DD) - m * m + 1e-5f);
    #pragma unroll
    for (int i = 0; i < 4; i++) {
      int d = lane + i * 64;
      hT[d][r] = (xv[i] - m) * rs * g2[d] + b2[d];
    }
  }
  __syncthreads();

  // y = gelu(h @ Wf1 + bf1)
  for (int jj = 0; jj < 2; jj++) {
    int j = t + jj * 256;
    float acc[R1];
    #pragma unroll
    for (int r = 0; r < R1; r++) acc[r] = bf1[j];
    for (int d = 0; d < DD; d++) {
      float w = Wf1[d * 512 + j];
      #pragma unroll
      for (int r = 0; r < R1; r++) acc[r] += hT[d][r] * w;
    }
    #pragma unroll
    for (int r = 0; r < R1; r++) {
      float v = acc[r];
      yT[j][r] = v * 0.5f * (1.f + erff(v * 0.70710678118654752f));
    }
  }
  __syncthreads();

  // out = xmid + y @ Wf2 + bf2
  {
    float acc[R1];
    #pragma unroll
    for (int r = 0; r < R1; r++) acc[r] = bf2[t];
    for (int e = 0; e < 2 * DD; e++) {
      float w = Wf2[e * DD + t];
      #pragma unroll
      for (int r = 0; r < R1; r++) acc[r] += yT[e][r] * w;
    }
    #pragma unroll
    for (int r = 0; r < R1; r++)
      out[(row0 + r) * DD + t] = xmid[(row0 + r) * DD + t] + acc[r];
  }
}

extern "C" void kernel_launch(void* const* d_in, const int* in_sizes, int n_in,
                              void* d_out, int out_size, void* d_ws, size_t ws_size,
                              hipStream_t stream) {
  const float* x      = (const float*)d_in[0];
  const int*   knn    = (const int*)  d_in[1];
  const float* relpos = (const float*)d_in[2];
  const float* g1     = (const float*)d_in[3];
  const float* b1     = (const float*)d_in[4];
  const float* g2     = (const float*)d_in[5];
  const float* b2     = (const float*)d_in[6];
  const float* Wq     = (const float*)d_in[7];
  const float* bq     = (const float*)d_in[8];
  const float* Wk     = (const float*)d_in[9];
  const float* bk     = (const float*)d_in[10];
  const float* Wv     = (const float*)d_in[11];
  const float* bv     = (const float*)d_in[12];
  const float* Wo     = (const float*)d_in[13];
  const float* bo     = (const float*)d_in[14];
  const float* Wpa1   = (const float*)d_in[15];
  const float* bpa1   = (const float*)d_in[16];
  const float* Wpa2   = (const float*)d_in[17];
  const float* bpa2   = (const float*)d_in[18];
  const float* Wpv1   = (const float*)d_in[19];
  const float* bpv1   = (const float*)d_in[20];
  const float* Wpv2   = (const float*)d_in[21];
  const float* bpv2   = (const float*)d_in[22];
  const float* Ws1    = (const float*)d_in[23];
  const float* bs1    = (const float*)d_in[24];
  const float* Ws2    = (const float*)d_in[25];
  const float* bs2    = (const float*)d_in[26];
  const float* Wf1    = (const float*)d_in[27];
  const float* bf1    = (const float*)d_in[28];
  const float* Wf2    = (const float*)d_in[29];
  const float* bf2    = (const float*)d_in[30];

  float* ws   = (float*)d_ws;
  float* q    = ws;
  float* kk   = q  + (size_t)BB * NN * AA;
  float* vv   = kk + (size_t)BB * NN * AA;
  float* xmid = vv + (size_t)BB * NN * VV;

  k_ln_qkv<<<(BB * NN) / R1, 256, 0, stream>>>(x, g1, b1, Wq, bq, Wk, bk, Wv, bv, q, kk, vv);
  k_attn<<<NN, 256, 0, stream>>>(x, relpos, knn, q, kk, vv,
                                 Wpa1, bpa1, Wpa2, bpa2, Wpv1, bpv1, Wpv2, bpv2,
                                 Ws1, bs1, Ws2, bs2, Wo, bo, xmid);
  k_ffn<<<(BB * NN) / R1, 256, 0, stream>>>(xmid, g2, b2, Wf1, bf1, Wf2, bf2, (float*)d_out);
}

// Round 2
// 1226.546 us; speedup vs baseline: 1.6017x; 1.6017x over previous
//
#include <hip/hip_runtime.h>
#include <hip/hip_bf16.h>
#include <math.h>

#define BB 2
#define NN 32768
#define KK 16
#define DD 256
#define AA 64
#define VV 64
#define R1 8

typedef __attribute__((ext_vector_type(8))) short bf16x8;
typedef __attribute__((ext_vector_type(4))) float f32x4;

__device__ __forceinline__ ushort f2bf(float v) {
  __hip_bfloat16 b = __float2bfloat16(v);
  ushort u; __builtin_memcpy(&u, &b, 2);
  return u;
}

// store one bf16 element into swizzled [16][64] bf16 tile
__device__ __forceinline__ void astore(ushort* A, int k, int a, float v) {
  int off = (k * 128 + a * 2) ^ ((k & 7) << 4);
  *reinterpret_cast<ushort*>(reinterpret_cast<char*>(A) + off) = f2bf(v);
}

// read A fragment (row = lane&15, k = s*32 + 8*(lane>>4) + e) from swizzled tile
__device__ __forceinline__ bf16x8 afrag(const ushort* A, int lane, int s) {
  int row = lane & 15, g = lane >> 4;
  int off = (row * 128 + s * 64 + g * 16) ^ ((row & 7) << 4);
  return *reinterpret_cast<const bf16x8*>(reinterpret_cast<const char*>(A) + off);
}

// load B fragment from a row-major 64x64 f32 weight matrix (k = s*32+8g+e, col)
__device__ __forceinline__ bf16x8 bfrag(const float* W, int lane, int wcol0, int s) {
  int g = lane >> 4, c = wcol0 + (lane & 15);
  bf16x8 f;
#pragma unroll
  for (int e = 0; e < 8; e++) {
    f[e] = (short)f2bf(W[(s * 32 + g * 8 + e) * 64 + c]);
  }
  return f;
}

// ---------------- Kernel 1: LN1 + QKV projection (8 rows / block) ----------------
__global__ __launch_bounds__(256) void k_ln_qkv(
    const float* __restrict__ x, const float* __restrict__ g1, const float* __restrict__ b1,
    const float* __restrict__ Wq, const float* __restrict__ bq,
    const float* __restrict__ Wk, const float* __restrict__ bk,
    const float* __restrict__ Wv, const float* __restrict__ bv,
    float* __restrict__ qo, float* __restrict__ ko, float* __restrict__ vo) {
  __shared__ float hT[DD][R1];
  int t = threadIdx.x;
  int lane = t & 63, wid = t >> 6;
  size_t row0 = (size_t)blockIdx.x * R1;

  for (int rr = 0; rr < 2; rr++) {
    int r = wid + rr * 4;
    size_t row = row0 + r;
    float xv[4]; float s = 0.f, s2 = 0.f;
#pragma unroll
    for (int i = 0; i < 4; i++) {
      xv[i] = x[row * DD + lane + i * 64];
      s += xv[i]; s2 += xv[i] * xv[i];
    }
    for (int off = 32; off > 0; off >>= 1) {
      s  += __shfl_down(s, off, 64);
      s2 += __shfl_down(s2, off, 64);
    }
    s = __shfl(s, 0, 64); s2 = __shfl(s2, 0, 64);
    float m = s * (1.f / DD);
    float rs = rsqrtf(s2 * (1.f / DD) - m * m + 1e-5f);
#pragma unroll
    for (int i = 0; i < 4; i++) {
      int d = lane + i * 64;
      hT[d][r] = (xv[i] - m) * rs * g1[d] + b1[d];
    }
  }
  __syncthreads();

  if (t < 192) {
    int grp = t >> 6, a = t & 63;
    const float* W    = (grp == 0) ? Wq : (grp == 1) ? Wk : Wv;
    const float* bias = (grp == 0) ? bq : (grp == 1) ? bk : bv;
    float acc[R1];
#pragma unroll
    for (int r = 0; r < R1; r++) acc[r] = bias[a];
    for (int d = 0; d < DD; d++) {
      float w = W[d * AA + a];
#pragma unroll
      for (int r = 0; r < R1; r++) acc[r] += hT[d][r] * w;
    }
    float* out = (grp == 0) ? qo : (grp == 1) ? ko : vo;
#pragma unroll
    for (int r = 0; r < R1; r++) out[(row0 + r) * AA + a] = acc[r];
  }
}

// ---------------- Kernel 2: per-point attention with MFMA (one block per n) ----------------
__global__ __launch_bounds__(256) void k_attn(
    const float* __restrict__ x, const float* __restrict__ relpos, const int* __restrict__ knn,
    const float* __restrict__ qg, const float* __restrict__ kg, const float* __restrict__ vg,
    const float* __restrict__ Wpa1, const float* __restrict__ bpa1,
    const float* __restrict__ Wpa2, const float* __restrict__ bpa2,
    const float* __restrict__ Wpv1, const float* __restrict__ bpv1,
    const float* __restrict__ Wpv2, const float* __restrict__ bpv2,
    const float* __restrict__ Ws1, const float* __restrict__ bs1,
    const float* __restrict__ Ws2, const float* __restrict__ bs2,
    const float* __restrict__ Wo, const float* __restrict__ bo,
    float* __restrict__ xmid) {
  int n = blockIdx.x;
  int t = threadIdx.x;
  int lane = t & 63, w = t >> 6;

  __shared__ __align__(16) ushort A0[16 * 64];   // bf16 swizzled activation tile
  __shared__ __align__(16) ushort A1[16 * 64];
  __shared__ float ra_ls[16][68];
  __shared__ float rv_ls[16][68];
  __shared__ float hid_ls[16][68];
  __shared__ __align__(16) float qv[64];
  __shared__ float ctxp[4][64];
  __shared__ __align__(16) float ctxv[64];
  __shared__ float attn_s[16];
  __shared__ float sc_s[16];
  __shared__ float rp_s[48];
  __shared__ int   idx_s[16];

  // persistent B fragments (bf16 weights in registers)
  bf16x8 fpa2_0 = bfrag(Wpa2, lane, w * 16, 0), fpa2_1 = bfrag(Wpa2, lane, w * 16, 1);
  bf16x8 fpv2_0 = bfrag(Wpv2, lane, w * 16, 0), fpv2_1 = bfrag(Wpv2, lane, w * 16, 1);
  bf16x8 fs1_0  = bfrag(Ws1,  lane, w * 16, 0), fs1_1  = bfrag(Ws1,  lane, w * 16, 1);

  if (t < 16) idx_s[t] = knn[n * KK + t];
  if (t >= 64 && t < 112) rp_s[t - 64] = relpos[(size_t)n * 48 + (t - 64)];
  __syncthreads();

  // rel-pos MLP hidden layers (elementwise) -> A0 (attn), A1 (value)
  {
    int a = t & 63, kb = t >> 6;
    float wa0 = Wpa1[a], wa1 = Wpa1[64 + a], wa2 = Wpa1[128 + a], ba = bpa1[a];
    float wv0 = Wpv1[a], wv1 = Wpv1[64 + a], wv2 = Wpv1[128 + a], bvv = bpv1[a];
#pragma unroll
    for (int j = 0; j < 4; j++) {
      int k = kb * 4 + j;
      float r0 = rp_s[k * 3], r1 = rp_s[k * 3 + 1], r2 = rp_s[k * 3 + 2];
      astore(A0, k, a, fmaxf(ba + r0 * wa0 + r1 * wa1 + r2 * wa2, 0.f));
      astore(A1, k, a, fmaxf(bvv + r0 * wv0 + r1 * wv1 + r2 * wv2, 0.f));
    }
  }
  __syncthreads();

  // ra = hidA @ Wpa2 + bpa2 ; rv = hidV @ Wpv2 + bpv2  (MFMA)
  {
    bf16x8 a0 = afrag(A0, lane, 0), a1 = afrag(A0, lane, 1);
    f32x4 acc = {0.f, 0.f, 0.f, 0.f};
    acc = __builtin_amdgcn_mfma_f32_16x16x32_bf16(a0, fpa2_0, acc, 0, 0, 0);
    acc = __builtin_amdgcn_mfma_f32_16x16x32_bf16(a1, fpa2_1, acc, 0, 0, 0);
    int col = w * 16 + (lane & 15), g = lane >> 4;
    float bias = bpa2[col];
#pragma unroll
    for (int r = 0; r < 4; r++) ra_ls[g * 4 + r][col] = acc[r] + bias;

    bf16x8 v0 = afrag(A1, lane, 0), v1 = afrag(A1, lane, 1);
    f32x4 accv = {0.f, 0.f, 0.f, 0.f};
    accv = __builtin_amdgcn_mfma_f32_16x16x32_bf16(v0, fpv2_0, accv, 0, 0, 0);
    accv = __builtin_amdgcn_mfma_f32_16x16x32_bf16(v1, fpv2_1, accv, 0, 0, 0);
    float biasv = bpv2[col];
#pragma unroll
    for (int r = 0; r < 4; r++) rv_ls[g * 4 + r][col] = accv[r] + biasv;
  }

  for (int b = 0; b < BB; b++) {
    size_t rowbase = (size_t)b * NN + n;
    if (t < 64) qv[t] = qg[rowbase * AA + t];
    __syncthreads();   // covers ra/rv writes (b=0), qv, and buffer reuse

    // tl = tanh(q - kn + ra) -> A0 (bf16 swizzled)
    {
      int a = t & 63, kb = t >> 6;
#pragma unroll
      for (int j = 0; j < 4; j++) {
        int k = kb * 4 + j;
        float kvv = kg[((size_t)b * NN + idx_s[k]) * AA + a];
        float xx = qv[a] - kvv + ra_ls[k][a];
        float ex = __expf(2.f * xx);
        float tv = 1.f - 2.f * __builtin_amdgcn_rcpf(ex + 1.f);
        astore(A0, k, a, tv);
      }
    }
    __syncthreads();

    // hid = relu(tl @ Ws1 + bs1)  (MFMA)
    {
      bf16x8 a0 = afrag(A0, lane, 0), a1 = afrag(A0, lane, 1);
      f32x4 acc = {0.f, 0.f, 0.f, 0.f};
      acc = __builtin_amdgcn_mfma_f32_16x16x32_bf16(a0, fs1_0, acc, 0, 0, 0);
      acc = __builtin_amdgcn_mfma_f32_16x16x32_bf16(a1, fs1_1, acc, 0, 0, 0);
      int col = w * 16 + (lane & 15), g = lane >> 4;
      float bias = bs1[col];
#pragma unroll
      for (int r = 0; r < 4; r++) hid_ls[g * 4 + r][col] = fmaxf(acc[r] + bias, 0.f);
    }
    __syncthreads();

    // score[k] = (hid[k] . Ws2 + bs2) / 8
    {
      int k = t >> 4, c = t & 15;
      const float4 wv2 = *reinterpret_cast<const float4*>(&Ws2[c * 4]);
      const float4 hv  = *reinterpret_cast<const float4*>(&hid_ls[k][c * 4]);
      float p = hv.x * wv2.x + hv.y * wv2.y + hv.z * wv2.z + hv.w * wv2.w;
#pragma unroll
      for (int o = 1; o < 16; o <<= 1) p += __shfl_xor(p, o, 64);
      if ((lane & 15) == 0) sc_s[k] = (p + bs2[0]) * 0.125f;
    }
    __syncthreads();

    if (t < 16) {
      float s = sc_s[t];
      float mx = s;
#pragma unroll
      for (int o = 8; o > 0; o >>= 1) mx = fmaxf(mx, __shfl_xor(mx, o, 64));
      float e = __expf(s - mx);
      float ssum = e;
#pragma unroll
      for (int o = 8; o > 0; o >>= 1) ssum += __shfl_xor(ssum, o, 64);
      attn_s[t] = e / ssum;
    }
    __syncthreads();

    // ctx partials over k-chunks
    {
      int v = t & 63, kb = t >> 6;
      float p = 0.f;
#pragma unroll
      for (int j = 0; j < 4; j++) {
        int k = kb * 4 + j;
        float vn = vg[((size_t)b * NN + idx_s[k]) * VV + v];
        p += attn_s[k] * (vn + rv_ls[k][v]);
      }
      ctxp[kb][v] = p;
    }
    __syncthreads();
    if (t < 64) ctxv[t] = ctxp[0][t] + ctxp[1][t] + ctxp[2][t] + ctxp[3][t];
    __syncthreads();

    // xmid = x + ctx @ Wo + bo
    {
      float acc = bo[t];
#pragma unroll
      for (int v4 = 0; v4 < 16; v4++) {
        float4 c4 = *reinterpret_cast<const float4*>(&ctxv[v4 * 4]);
        acc = fmaf(c4.x, Wo[(v4 * 4 + 0) * DD + t], acc);
        acc = fmaf(c4.y, Wo[(v4 * 4 + 1) * DD + t], acc);
        acc = fmaf(c4.z, Wo[(v4 * 4 + 2) * DD + t], acc);
        acc = fmaf(c4.w, Wo[(v4 * 4 + 3) * DD + t], acc);
      }
      size_t rb = rowbase * DD + t;
      xmid[rb] = x[rb] + acc;
    }
    __syncthreads();
  }
}

// ---------------- Kernel 3: LN2 + FFN + residual (8 rows / block) ----------------
__global__ __launch_bounds__(256) void k_ffn(
    const float* __restrict__ xmid, const float* __restrict__ g2, const float* __restrict__ b2,
    const float* __restrict__ Wf1, const float* __restrict__ bf1,
    const float* __restrict__ Wf2, const float* __restrict__ bf2,
    float* __restrict__ out) {
  __shared__ float hT[DD][R1];
  __shared__ float yT[2 * DD][R1];
  int t = threadIdx.x;
  int lane = t & 63, wid = t >> 6;
  size_t row0 = (size_t)blockIdx.x * R1;

  for (int rr = 0; rr < 2; rr++) {
    int r = wid + rr * 4;
    size_t row = row0 + r;
    float xv[4]; float s = 0.f, s2 = 0.f;
#pragma unroll
    for (int i = 0; i < 4; i++) {
      xv[i] = xmid[row * DD + lane + i * 64];
      s += xv[i]; s2 += xv[i] * xv[i];
    }
    for (int off = 32; off > 0; off >>= 1) {
      s  += __shfl_down(s, off, 64);
      s2 += __shfl_down(s2, off, 64);
    }
    s = __shfl(s, 0, 64); s2 = __shfl(s2, 0, 64);
    float m = s * (1.f / DD);
    float rs = rsqrtf(s2 * (1.f / DD) - m * m + 1e-5f);
#pragma unroll
    for (int i = 0; i < 4; i++) {
      int d = lane + i * 64;
      hT[d][r] = (xv[i] - m) * rs * g2[d] + b2[d];
    }
  }
  __syncthreads();

  for (int jj = 0; jj < 2; jj++) {
    int j = t + jj * 256;
    float acc[R1];
#pragma unroll
    for (int r = 0; r < R1; r++) acc[r] = bf1[j];
    for (int d = 0; d < DD; d++) {
      float w = Wf1[d * 512 + j];
#pragma unroll
      for (int r = 0; r < R1; r++) acc[r] += hT[d][r] * w;
    }
#pragma unroll
    for (int r = 0; r < R1; r++) {
      float v = acc[r];
      yT[j][r] = v * 0.5f * (1.f + erff(v * 0.70710678118654752f));
    }
  }
  __syncthreads();

  {
    float acc[R1];
#pragma unroll
    for (int r = 0; r < R1; r++) acc[r] = bf2[t];
    for (int e = 0; e < 2 * DD; e++) {
      float w = Wf2[e * DD + t];
#pragma unroll
      for (int r = 0; r < R1; r++) acc[r] += yT[e][r] * w;
    }
#pragma unroll
    for (int r = 0; r < R1; r++)
      out[(row0 + r) * DD + t] = xmid[(row0 + r) * DD + t] + acc[r];
  }
}

extern "C" void kernel_launch(void* const* d_in, const int* in_sizes, int n_in,
                              void* d_out, int out_size, void* d_ws, size_t ws_size,
                              hipStream_t stream) {
  const float* x      = (const float*)d_in[0];
  const int*   knn    = (const int*)  d_in[1];
  const float* relpos = (const float*)d_in[2];
  const float* g1     = (const float*)d_in[3];
  const float* b1     = (const float*)d_in[4];
  const float* g2     = (const float*)d_in[5];
  const float* b2     = (const float*)d_in[6];
  const float* Wq     = (const float*)d_in[7];
  const float* bq     = (const float*)d_in[8];
  const float* Wk     = (const float*)d_in[9];
  const float* bk     = (const float*)d_in[10];
  const float* Wv     = (const float*)d_in[11];
  const float* bv     = (const float*)d_in[12];
  const float* Wo     = (const float*)d_in[13];
  const float* bo     = (const float*)d_in[14];
  const float* Wpa1   = (const float*)d_in[15];
  const float* bpa1   = (const float*)d_in[16];
  const float* Wpa2   = (const float*)d_in[17];
  const float* bpa2   = (const float*)d_in[18];
  const float* Wpv1   = (const float*)d_in[19];
  const float* bpv1   = (const float*)d_in[20];
  const float* Wpv2   = (const float*)d_in[21];
  const float* bpv2   = (const float*)d_in[22];
  const float* Ws1    = (const float*)d_in[23];
  const float* bs1    = (const float*)d_in[24];
  const float* Ws2    = (const float*)d_in[25];
  const float* bs2    = (const float*)d_in[26];
  const float* Wf1    = (const float*)d_in[27];
  const float* bf1    = (const float*)d_in[28];
  const float* Wf2    = (const float*)d_in[29];
  const float* bf2    = (const float*)d_in[30];

  float* ws   = (float*)d_ws;
  float* q    = ws;
  float* kk   = q  + (size_t)BB * NN * AA;
  float* vv   = kk + (size_t)BB * NN * AA;
  float* xmid = vv + (size_t)BB * NN * VV;

  k_ln_qkv<<<(BB * NN) / R1, 256, 0, stream>>>(x, g1, b1, Wq, bq, Wk, bk, Wv, bv, q, kk, vv);
  k_attn<<<NN, 256, 0, stream>>>(x, relpos, knn, q, kk, vv,
                                 Wpa1, bpa1, Wpa2, bpa2, Wpv1, bpv1, Wpv2, bpv2,
                                 Ws1, bs1, Ws2, bs2, Wo, bo, xmid);
  k_ffn<<<(BB * NN) / R1, 256, 0, stream>>>(xmid, g2, b2, Wf1, bf1, Wf2, bf2, (float*)d_out);
}

// Round 3
// 711.110 us; speedup vs baseline: 2.7628x; 1.7248x over previous
//
#include <hip/hip_runtime.h>
#include <hip/hip_bf16.h>
#include <math.h>

#define BB 2
#define NN 32768
#define KK 16
#define DD 256
#define AA 64
#define VV 64

typedef __attribute__((ext_vector_type(8))) short bf16x8;
typedef __attribute__((ext_vector_type(4))) float f32x4;
typedef __attribute__((ext_vector_type(4))) unsigned short u16x4;

__device__ __forceinline__ ushort f2bf(float v) {
  __hip_bfloat16 b = __float2bfloat16(v);
  ushort u; __builtin_memcpy(&u, &b, 2);
  return u;
}

// ---------------- Kernel 0: pack weights into bf16 B-fragment order ----------------
// layout: [ks][ntile][lane][8], element (lane,e) = W[ks*32 + (lane>>4)*8 + e][ntile*16 + (lane&15)]
__global__ __launch_bounds__(256) void k_prep(
    const float* __restrict__ Wq, const float* __restrict__ Wk, const float* __restrict__ Wv,
    const float* __restrict__ Wf1, const float* __restrict__ Wf2,
    ushort* __restrict__ pQKV, ushort* __restrict__ pWf1, ushort* __restrict__ pWf2) {
  int tid = blockIdx.x * 256 + threadIdx.x;
  int lane = tid & 63, g = lane >> 4, c16 = lane & 15;
  bf16x8 f;
  if (tid < 6144) {                       // QKV: 8 ks x 12 nt
    int fi = tid >> 6; int ks = fi / 12, nt = fi % 12;
    int col = nt * 16 + c16;
    const float* W = (col < 64) ? Wq : (col < 128) ? Wk : Wv;
    int c = col & 63;
#pragma unroll
    for (int e = 0; e < 8; e++) f[e] = (short)f2bf(W[(ks * 32 + g * 8 + e) * 64 + c]);
    *reinterpret_cast<bf16x8*>(&pQKV[(size_t)tid * 8]) = f;
  } else if (tid < 6144 + 16384) {        // Wf1: 8 ks x 32 nt
    int t2 = tid - 6144; int fi = t2 >> 6; int ks = fi >> 5, nt = fi & 31;
    int col = nt * 16 + c16;
#pragma unroll
    for (int e = 0; e < 8; e++) f[e] = (short)f2bf(Wf1[(ks * 32 + g * 8 + e) * 512 + col]);
    *reinterpret_cast<bf16x8*>(&pWf1[(size_t)t2 * 8]) = f;
  } else if (tid < 38912) {               // Wf2: 16 ks x 16 nt
    int t3 = tid - 22528; int fi = t3 >> 6; int ks = fi >> 4, nt = fi & 15;
    int col = nt * 16 + c16;
#pragma unroll
    for (int e = 0; e < 8; e++) f[e] = (short)f2bf(Wf2[(ks * 32 + g * 8 + e) * 256 + col]);
    *reinterpret_cast<bf16x8*>(&pWf2[(size_t)t3 * 8]) = f;
  }
}

// ---------------- Kernel 1: LN1 + QKV projection (MFMA, 32 rows / block) ----------------
__global__ __launch_bounds__(256) void k_qkv(
    const float* __restrict__ x, const float* __restrict__ g1, const float* __restrict__ b1,
    const ushort* __restrict__ pW,
    const float* __restrict__ bq, const float* __restrict__ bk, const float* __restrict__ bv,
    float* __restrict__ qo, float* __restrict__ ko, float* __restrict__ vo) {
  __shared__ __align__(16) ushort hs[32 * 256];   // 16KB, swizzled, row stride 512B
  int t = threadIdx.x, lane = t & 63, w = t >> 6;
  size_t row0 = (size_t)blockIdx.x * 32;

  // LN1: wave w handles rows w*8 .. w*8+7
  {
    const float4 gv = *reinterpret_cast<const float4*>(&g1[lane * 4]);
    const float4 bvv = *reinterpret_cast<const float4*>(&b1[lane * 4]);
#pragma unroll
    for (int r8 = 0; r8 < 8; r8++) {
      int r = w * 8 + r8;
      const float4 xv = *reinterpret_cast<const float4*>(&x[(row0 + r) * DD + lane * 4]);
      float s = xv.x + xv.y + xv.z + xv.w;
      float s2 = xv.x * xv.x + xv.y * xv.y + xv.z * xv.z + xv.w * xv.w;
      for (int o = 32; o > 0; o >>= 1) { s += __shfl_down(s, o, 64); s2 += __shfl_down(s2, o, 64); }
      s = __shfl(s, 0, 64); s2 = __shfl(s2, 0, 64);
      float m = s * (1.f / DD), rs = rsqrtf(s2 * (1.f / DD) - m * m + 1e-5f);
      u16x4 hv;
      hv[0] = f2bf((xv.x - m) * rs * gv.x + bvv.x);
      hv[1] = f2bf((xv.y - m) * rs * gv.y + bvv.y);
      hv[2] = f2bf((xv.z - m) * rs * gv.z + bvv.z);
      hv[3] = f2bf((xv.w - m) * rs * gv.w + bvv.w);
      int off = (r * 512 + lane * 8) ^ ((r & 7) << 4);
      *reinterpret_cast<u16x4*>(reinterpret_cast<char*>(hs) + off) = hv;
    }
  }
  __syncthreads();

  // GEMM: [32 x 256] @ [256 x 192], wave owns 3 n-tiles
  f32x4 acc[2][3] = {};
  for (int ks = 0; ks < 8; ks++) {
    int rowa = lane & 15, g = lane >> 4;
    bf16x8 a0 = *reinterpret_cast<const bf16x8*>(reinterpret_cast<const char*>(hs) +
                 ((rowa * 512 + ks * 64 + g * 16) ^ ((rowa & 7) << 4)));
    int rowb = rowa + 16;
    bf16x8 a1 = *reinterpret_cast<const bf16x8*>(reinterpret_cast<const char*>(hs) +
                 ((rowb * 512 + ks * 64 + g * 16) ^ ((rowb & 7) << 4)));
#pragma unroll
    for (int j = 0; j < 3; j++) {
      int fi = ks * 12 + w * 3 + j;
      bf16x8 bw = *reinterpret_cast<const bf16x8*>(&pW[((size_t)fi * 64 + lane) * 8]);
      acc[0][j] = __builtin_amdgcn_mfma_f32_16x16x32_bf16(a0, bw, acc[0][j], 0, 0, 0);
      acc[1][j] = __builtin_amdgcn_mfma_f32_16x16x32_bf16(a1, bw, acc[1][j], 0, 0, 0);
    }
  }

#pragma unroll
  for (int j = 0; j < 3; j++) {
    int ntg = w * 3 + j;
    int buf = ntg >> 2;
    float* out = (buf == 0) ? qo : (buf == 1) ? ko : vo;
    const float* bias = (buf == 0) ? bq : (buf == 1) ? bk : bv;
    int col = (ntg & 3) * 16 + (lane & 15);
    float bb = bias[col];
#pragma unroll
    for (int mt = 0; mt < 2; mt++)
#pragma unroll
      for (int r = 0; r < 4; r++) {
        int row = mt * 16 + (lane >> 4) * 4 + r;
        out[(row0 + row) * 64 + col] = acc[mt][j][r] + bb;
      }
  }
}

// ---------------- Kernel 2: per-point attention with MFMA (unchanged from round 2) ----------------
__device__ __forceinline__ void astore(ushort* A, int k, int a, float v) {
  int off = (k * 128 + a * 2) ^ ((k & 7) << 4);
  *reinterpret_cast<ushort*>(reinterpret_cast<char*>(A) + off) = f2bf(v);
}
__device__ __forceinline__ bf16x8 afrag(const ushort* A, int lane, int s) {
  int row = lane & 15, g = lane >> 4;
  int off = (row * 128 + s * 64 + g * 16) ^ ((row & 7) << 4);
  return *reinterpret_cast<const bf16x8*>(reinterpret_cast<const char*>(A) + off);
}
__device__ __forceinline__ bf16x8 bfrag(const float* W, int lane, int wcol0, int s) {
  int g = lane >> 4, c = wcol0 + (lane & 15);
  bf16x8 f;
#pragma unroll
  for (int e = 0; e < 8; e++) f[e] = (short)f2bf(W[(s * 32 + g * 8 + e) * 64 + c]);
  return f;
}

__global__ __launch_bounds__(256) void k_attn(
    const float* __restrict__ x, const float* __restrict__ relpos, const int* __restrict__ knn,
    const float* __restrict__ qg, const float* __restrict__ kg, const float* __restrict__ vg,
    const float* __restrict__ Wpa1, const float* __restrict__ bpa1,
    const float* __restrict__ Wpa2, const float* __restrict__ bpa2,
    const float* __restrict__ Wpv1, const float* __restrict__ bpv1,
    const float* __restrict__ Wpv2, const float* __restrict__ bpv2,
    const float* __restrict__ Ws1, const float* __restrict__ bs1,
    const float* __restrict__ Ws2, const float* __restrict__ bs2,
    const float* __restrict__ Wo, const float* __restrict__ bo,
    float* __restrict__ xmid) {
  int n = blockIdx.x;
  int t = threadIdx.x;
  int lane = t & 63, w = t >> 6;

  __shared__ __align__(16) ushort A0[16 * 64];
  __shared__ __align__(16) ushort A1[16 * 64];
  __shared__ float ra_ls[16][68];
  __shared__ float rv_ls[16][68];
  __shared__ float hid_ls[16][68];
  __shared__ __align__(16) float qv[64];
  __shared__ float ctxp[4][64];
  __shared__ __align__(16) float ctxv[64];
  __shared__ float attn_s[16];
  __shared__ float sc_s[16];
  __shared__ float rp_s[48];
  __shared__ int   idx_s[16];

  bf16x8 fpa2_0 = bfrag(Wpa2, lane, w * 16, 0), fpa2_1 = bfrag(Wpa2, lane, w * 16, 1);
  bf16x8 fpv2_0 = bfrag(Wpv2, lane, w * 16, 0), fpv2_1 = bfrag(Wpv2, lane, w * 16, 1);
  bf16x8 fs1_0  = bfrag(Ws1,  lane, w * 16, 0), fs1_1  = bfrag(Ws1,  lane, w * 16, 1);

  if (t < 16) idx_s[t] = knn[n * KK + t];
  if (t >= 64 && t < 112) rp_s[t - 64] = relpos[(size_t)n * 48 + (t - 64)];
  __syncthreads();

  {
    int a = t & 63, kb = t >> 6;
    float wa0 = Wpa1[a], wa1 = Wpa1[64 + a], wa2 = Wpa1[128 + a], ba = bpa1[a];
    float wv0 = Wpv1[a], wv1 = Wpv1[64 + a], wv2 = Wpv1[128 + a], bvv = bpv1[a];
#pragma unroll
    for (int j = 0; j < 4; j++) {
      int k = kb * 4 + j;
      float r0 = rp_s[k * 3], r1 = rp_s[k * 3 + 1], r2 = rp_s[k * 3 + 2];
      astore(A0, k, a, fmaxf(ba + r0 * wa0 + r1 * wa1 + r2 * wa2, 0.f));
      astore(A1, k, a, fmaxf(bvv + r0 * wv0 + r1 * wv1 + r2 * wv2, 0.f));
    }
  }
  __syncthreads();

  {
    bf16x8 a0 = afrag(A0, lane, 0), a1 = afrag(A0, lane, 1);
    f32x4 acc = {0.f, 0.f, 0.f, 0.f};
    acc = __builtin_amdgcn_mfma_f32_16x16x32_bf16(a0, fpa2_0, acc, 0, 0, 0);
    acc = __builtin_amdgcn_mfma_f32_16x16x32_bf16(a1, fpa2_1, acc, 0, 0, 0);
    int col = w * 16 + (lane & 15), g = lane >> 4;
    float bias = bpa2[col];
#pragma unroll
    for (int r = 0; r < 4; r++) ra_ls[g * 4 + r][col] = acc[r] + bias;

    bf16x8 v0 = afrag(A1, lane, 0), v1 = afrag(A1, lane, 1);
    f32x4 accv = {0.f, 0.f, 0.f, 0.f};
    accv = __builtin_amdgcn_mfma_f32_16x16x32_bf16(v0, fpv2_0, accv, 0, 0, 0);
    accv = __builtin_amdgcn_mfma_f32_16x16x32_bf16(v1, fpv2_1, accv, 0, 0, 0);
    float biasv = bpv2[col];
#pragma unroll
    for (int r = 0; r < 4; r++) rv_ls[g * 4 + r][col] = accv[r] + biasv;
  }

  for (int b = 0; b < BB; b++) {
    size_t rowbase = (size_t)b * NN + n;
    if (t < 64) qv[t] = qg[rowbase * AA + t];
    __syncthreads();

    {
      int a = t & 63, kb = t >> 6;
#pragma unroll
      for (int j = 0; j < 4; j++) {
        int k = kb * 4 + j;
        float kvv = kg[((size_t)b * NN + idx_s[k]) * AA + a];
        float xx = qv[a] - kvv + ra_ls[k][a];
        float ex = __expf(2.f * xx);
        float tv = 1.f - 2.f * __builtin_amdgcn_rcpf(ex + 1.f);
        astore(A0, k, a, tv);
      }
    }
    __syncthreads();

    {
      bf16x8 a0 = afrag(A0, lane, 0), a1 = afrag(A0, lane, 1);
      f32x4 acc = {0.f, 0.f, 0.f, 0.f};
      acc = __builtin_amdgcn_mfma_f32_16x16x32_bf16(a0, fs1_0, acc, 0, 0, 0);
      acc = __builtin_amdgcn_mfma_f32_16x16x32_bf16(a1, fs1_1, acc, 0, 0, 0);
      int col = w * 16 + (lane & 15), g = lane >> 4;
      float bias = bs1[col];
#pragma unroll
      for (int r = 0; r < 4; r++) hid_ls[g * 4 + r][col] = fmaxf(acc[r] + bias, 0.f);
    }
    __syncthreads();

    {
      int k = t >> 4, c = t & 15;
      const float4 wv2 = *reinterpret_cast<const float4*>(&Ws2[c * 4]);
      const float4 hv  = *reinterpret_cast<const float4*>(&hid_ls[k][c * 4]);
      float p = hv.x * wv2.x + hv.y * wv2.y + hv.z * wv2.z + hv.w * wv2.w;
#pragma unroll
      for (int o = 1; o < 16; o <<= 1) p += __shfl_xor(p, o, 64);
      if ((lane & 15) == 0) sc_s[k] = (p + bs2[0]) * 0.125f;
    }
    __syncthreads();

    if (t < 16) {
      float s = sc_s[t];
      float mx = s;
#pragma unroll
      for (int o = 8; o > 0; o >>= 1) mx = fmaxf(mx, __shfl_xor(mx, o, 64));
      float e = __expf(s - mx);
      float ssum = e;
#pragma unroll
      for (int o = 8; o > 0; o >>= 1) ssum += __shfl_xor(ssum, o, 64);
      attn_s[t] = e / ssum;
    }
    __syncthreads();

    {
      int v = t & 63, kb = t >> 6;
      float p = 0.f;
#pragma unroll
      for (int j = 0; j < 4; j++) {
        int k = kb * 4 + j;
        float vn = vg[((size_t)b * NN + idx_s[k]) * VV + v];
        p += attn_s[k] * (vn + rv_ls[k][v]);
      }
      ctxp[kb][v] = p;
    }
    __syncthreads();
    if (t < 64) ctxv[t] = ctxp[0][t] + ctxp[1][t] + ctxp[2][t] + ctxp[3][t];
    __syncthreads();

    {
      float acc = bo[t];
#pragma unroll
      for (int v4 = 0; v4 < 16; v4++) {
        float4 c4 = *reinterpret_cast<const float4*>(&ctxv[v4 * 4]);
        acc = fmaf(c4.x, Wo[(v4 * 4 + 0) * DD + t], acc);
        acc = fmaf(c4.y, Wo[(v4 * 4 + 1) * DD + t], acc);
        acc = fmaf(c4.z, Wo[(v4 * 4 + 2) * DD + t], acc);
        acc = fmaf(c4.w, Wo[(v4 * 4 + 3) * DD + t], acc);
      }
      size_t rb = rowbase * DD + t;
      xmid[rb] = x[rb] + acc;
    }
    __syncthreads();
  }
}

// ---------------- Kernel 3: LN2 + FFN + residual (MFMA, 32 rows / block) ----------------
__global__ __launch_bounds__(256) void k_ffn(
    const float* __restrict__ xmid, const float* __restrict__ g2, const float* __restrict__ b2,
    const ushort* __restrict__ pWf1, const float* __restrict__ bf1,
    const ushort* __restrict__ pWf2, const float* __restrict__ bf2,
    float* __restrict__ out) {
  __shared__ __align__(16) ushort hs[32 * 256];   // 16KB, row stride 512B
  __shared__ __align__(16) ushort ys[32 * 512];   // 32KB, row stride 1024B
  int t = threadIdx.x, lane = t & 63, w = t >> 6;
  size_t row0 = (size_t)blockIdx.x * 32;

  // LN2
  {
    const float4 gv = *reinterpret_cast<const float4*>(&g2[lane * 4]);
    const float4 bvv = *reinterpret_cast<const float4*>(&b2[lane * 4]);
#pragma unroll
    for (int r8 = 0; r8 < 8; r8++) {
      int r = w * 8 + r8;
      const float4 xv = *reinterpret_cast<const float4*>(&xmid[(row0 + r) * DD + lane * 4]);
      float s = xv.x + xv.y + xv.z + xv.w;
      float s2 = xv.x * xv.x + xv.y * xv.y + xv.z * xv.z + xv.w * xv.w;
      for (int o = 32; o > 0; o >>= 1) { s += __shfl_down(s, o, 64); s2 += __shfl_down(s2, o, 64); }
      s = __shfl(s, 0, 64); s2 = __shfl(s2, 0, 64);
      float m = s * (1.f / DD), rs = rsqrtf(s2 * (1.f / DD) - m * m + 1e-5f);
      u16x4 hv;
      hv[0] = f2bf((xv.x - m) * rs * gv.x + bvv.x);
      hv[1] = f2bf((xv.y - m) * rs * gv.y + bvv.y);
      hv[2] = f2bf((xv.z - m) * rs * gv.z + bvv.z);
      hv[3] = f2bf((xv.w - m) * rs * gv.w + bvv.w);
      int off = (r * 512 + lane * 8) ^ ((r & 7) << 4);
      *reinterpret_cast<u16x4*>(reinterpret_cast<char*>(hs) + off) = hv;
    }
  }
  __syncthreads();

  // GEMM1: [32 x 256] @ [256 x 512]; wave owns 8 n-tiles (128 cols)
  f32x4 acc1[2][8] = {};
  for (int ks = 0; ks < 8; ks++) {
    int rowa = lane & 15, g = lane >> 4;
    bf16x8 a0 = *reinterpret_cast<const bf16x8*>(reinterpret_cast<const char*>(hs) +
                 ((rowa * 512 + ks * 64 + g * 16) ^ ((rowa & 7) << 4)));
    int rowb = rowa + 16;
    bf16x8 a1 = *reinterpret_cast<const bf16x8*>(reinterpret_cast<const char*>(hs) +
                 ((rowb * 512 + ks * 64 + g * 16) ^ ((rowb & 7) << 4)));
#pragma unroll
    for (int j = 0; j < 8; j++) {
      int fi = ks * 32 + w * 8 + j;
      bf16x8 bw = *reinterpret_cast<const bf16x8*>(&pWf1[((size_t)fi * 64 + lane) * 8]);
      acc1[0][j] = __builtin_amdgcn_mfma_f32_16x16x32_bf16(a0, bw, acc1[0][j], 0, 0, 0);
      acc1[1][j] = __builtin_amdgcn_mfma_f32_16x16x32_bf16(a1, bw, acc1[1][j], 0, 0, 0);
    }
  }

  // epilogue1: bias + exact gelu -> ys (bf16, swizzled)
#pragma unroll
  for (int j = 0; j < 8; j++) {
    int col = w * 128 + j * 16 + (lane & 15);
    float bb = bf1[col];
#pragma unroll
    for (int mt = 0; mt < 2; mt++)
#pragma unroll
      for (int r = 0; r < 4; r++) {
        float v = acc1[mt][j][r] + bb;
        v = v * 0.5f * (1.f + erff(v * 0.70710678118654752f));
        int row = mt * 16 + (lane >> 4) * 4 + r;
        int off = (row * 1024 + col * 2) ^ ((row & 7) << 4);
        *reinterpret_cast<ushort*>(reinterpret_cast<char*>(ys) + off) = f2bf(v);
      }
  }
  __syncthreads();

  // GEMM2: [32 x 512] @ [512 x 256]; wave owns 4 n-tiles (64 cols)
  f32x4 acc2[2][4] = {};
  for (int ks = 0; ks < 16; ks++) {
    int rowa = lane & 15, g = lane >> 4;
    bf16x8 a0 = *reinterpret_cast<const bf16x8*>(reinterpret_cast<const char*>(ys) +
                 ((rowa * 1024 + ks * 64 + g * 16) ^ ((rowa & 7) << 4)));
    int rowb = rowa + 16;
    bf16x8 a1 = *reinterpret_cast<const bf16x8*>(reinterpret_cast<const char*>(ys) +
                 ((rowb * 1024 + ks * 64 + g * 16) ^ ((rowb & 7) << 4)));
#pragma unroll
    for (int j = 0; j < 4; j++) {
      int fi = ks * 16 + w * 4 + j;
      bf16x8 bw = *reinterpret_cast<const bf16x8*>(&pWf2[((size_t)fi * 64 + lane) * 8]);
      acc2[0][j] = __builtin_amdgcn_mfma_f32_16x16x32_bf16(a0, bw, acc2[0][j], 0, 0, 0);
      acc2[1][j] = __builtin_amdgcn_mfma_f32_16x16x32_bf16(a1, bw, acc2[1][j], 0, 0, 0);
    }
  }

  // epilogue2: residual + bias
#pragma unroll
  for (int j = 0; j < 4; j++) {
    int col = w * 64 + j * 16 + (lane & 15);
    float bb = bf2[col];
#pragma unroll
    for (int mt = 0; mt < 2; mt++)
#pragma unroll
      for (int r = 0; r < 4; r++) {
        int row = mt * 16 + (lane >> 4) * 4 + r;
        size_t idx = (row0 + row) * DD + col;
        out[idx] = xmid[idx] + acc2[mt][j][r] + bb;
      }
  }
}

extern "C" void kernel_launch(void* const* d_in, const int* in_sizes, int n_in,
                              void* d_out, int out_size, void* d_ws, size_t ws_size,
                              hipStream_t stream) {
  const float* x      = (const float*)d_in[0];
  const int*   knn    = (const int*)  d_in[1];
  const float* relpos = (const float*)d_in[2];
  const float* g1     = (const float*)d_in[3];
  const float* b1     = (const float*)d_in[4];
  const float* g2     = (const float*)d_in[5];
  const float* b2     = (const float*)d_in[6];
  const float* Wq     = (const float*)d_in[7];
  const float* bq     = (const float*)d_in[8];
  const float* Wk     = (const float*)d_in[9];
  const float* bk     = (const float*)d_in[10];
  const float* Wv     = (const float*)d_in[11];
  const float* bv     = (const float*)d_in[12];
  const float* Wo     = (const float*)d_in[13];
  const float* bo     = (const float*)d_in[14];
  const float* Wpa1   = (const float*)d_in[15];
  const float* bpa1   = (const float*)d_in[16];
  const float* Wpa2   = (const float*)d_in[17];
  const float* bpa2   = (const float*)d_in[18];
  const float* Wpv1   = (const float*)d_in[19];
  const float* bpv1   = (const float*)d_in[20];
  const float* Wpv2   = (const float*)d_in[21];
  const float* bpv2   = (const float*)d_in[22];
  const float* Ws1    = (const float*)d_in[23];
  const float* bs1    = (const float*)d_in[24];
  const float* Ws2    = (const float*)d_in[25];
  const float* bs2    = (const float*)d_in[26];
  const float* Wf1    = (const float*)d_in[27];
  const float* bf1    = (const float*)d_in[28];
  const float* Wf2    = (const float*)d_in[29];
  const float* bf2    = (const float*)d_in[30];

  float* ws   = (float*)d_ws;
  float* q    = ws;
  float* kk   = q  + (size_t)BB * NN * AA;
  float* vv   = kk + (size_t)BB * NN * AA;
  float* xmid = vv + (size_t)BB * NN * VV;
  ushort* pQKV = (ushort*)(xmid + (size_t)BB * NN * DD);
  ushort* pWf1 = pQKV + 49152;
  ushort* pWf2 = pWf1 + 131072;

  k_prep<<<152, 256, 0, stream>>>(Wq, Wk, Wv, Wf1, Wf2, pQKV, pWf1, pWf2);
  k_qkv<<<(BB * NN) / 32, 256, 0, stream>>>(x, g1, b1, pQKV, bq, bk, bv, q, kk, vv);
  k_attn<<<NN, 256, 0, stream>>>(x, relpos, knn, q, kk, vv,
                                 Wpa1, bpa1, Wpa2, bpa2, Wpv1, bpv1, Wpv2, bpv2,
                                 Ws1, bs1, Ws2, bs2, Wo, bo, xmid);
  k_ffn<<<(BB * NN) / 32, 256, 0, stream>>>(xmid, g2, b2, pWf1, bf1, pWf2, bf2, (float*)d_out);
}

// Round 4
// 474.195 us; speedup vs baseline: 4.1431x; 1.4996x over previous
//
#include <hip/hip_runtime.h>
#include <hip/hip_bf16.h>
#include <math.h>

#define BB 2
#define NN 32768
#define KK 16
#define DD 256
#define AA 64
#define VV 64

typedef __attribute__((ext_vector_type(8))) short bf16x8;
typedef __attribute__((ext_vector_type(4))) float f32x4;
typedef __attribute__((ext_vector_type(4))) unsigned short u16x4;

__device__ __forceinline__ ushort f2bf(float v) {
  __hip_bfloat16 b = __float2bfloat16(v);
  ushort u; __builtin_memcpy(&u, &b, 2);
  return u;
}

// swizzled bf16 tile helpers (row stride 128B, XOR swizzle (row&7)<<4)
__device__ __forceinline__ void astore(ushort* A, int row, int col, float v) {
  int off = (row * 128 + col * 2) ^ ((row & 7) << 4);
  *reinterpret_cast<ushort*>(reinterpret_cast<char*>(A) + off) = f2bf(v);
}
__device__ __forceinline__ void zstore8(ushort* A, int row, int chunk) {
  int off = (row * 128 + chunk * 8) ^ ((row & 7) << 4);
  *reinterpret_cast<unsigned long long*>(reinterpret_cast<char*>(A) + off) = 0ULL;
}
__device__ __forceinline__ bf16x8 afrag(const ushort* A, int rowbase, int lane, int ks) {
  int row = rowbase + (lane & 15), g = lane >> 4;
  int off = (row * 128 + ks * 64 + g * 16) ^ ((row & 7) << 4);
  return *reinterpret_cast<const bf16x8*>(reinterpret_cast<const char*>(A) + off);
}
__device__ __forceinline__ bf16x8 loadfrag(const ushort* p, int fi, int lane) {
  return *reinterpret_cast<const bf16x8*>(&p[((size_t)fi * 64 + lane) * 8]);
}

// ---------------- Kernel 0: pack weights into bf16 B-fragment order ----------------
__global__ __launch_bounds__(256) void k_prep(
    const float* __restrict__ Wq, const float* __restrict__ Wk, const float* __restrict__ Wv,
    const float* __restrict__ Wf1, const float* __restrict__ Wf2,
    const float* __restrict__ Wpa2, const float* __restrict__ Wpv2,
    const float* __restrict__ Ws1, const float* __restrict__ Wo,
    ushort* __restrict__ pQKV, ushort* __restrict__ pWf1, ushort* __restrict__ pWf2,
    ushort* __restrict__ pS, ushort* __restrict__ pWo) {
  int tid = blockIdx.x * 256 + threadIdx.x;
  int lane = tid & 63, g = lane >> 4, c16 = lane & 15;
  bf16x8 f;
  if (tid < 6144) {                       // QKV: 8 ks x 12 nt
    int fi = tid >> 6; int ks = fi / 12, nt = fi % 12;
    int col = nt * 16 + c16;
    const float* W = (col < 64) ? Wq : (col < 128) ? Wk : Wv;
    int c = col & 63;
#pragma unroll
    for (int e = 0; e < 8; e++) f[e] = (short)f2bf(W[(ks * 32 + g * 8 + e) * 64 + c]);
    *reinterpret_cast<bf16x8*>(&pQKV[(size_t)tid * 8]) = f;
  } else if (tid < 22528) {               // Wf1: 8 ks x 32 nt
    int t2 = tid - 6144; int fi = t2 >> 6; int ks = fi >> 5, nt = fi & 31;
    int col = nt * 16 + c16;
#pragma unroll
    for (int e = 0; e < 8; e++) f[e] = (short)f2bf(Wf1[(ks * 32 + g * 8 + e) * 512 + col]);
    *reinterpret_cast<bf16x8*>(&pWf1[(size_t)t2 * 8]) = f;
  } else if (tid < 38912) {               // Wf2: 16 ks x 16 nt
    int t3 = tid - 22528; int fi = t3 >> 6; int ks = fi >> 4, nt = fi & 15;
    int col = nt * 16 + c16;
#pragma unroll
    for (int e = 0; e < 8; e++) f[e] = (short)f2bf(Wf2[(ks * 32 + g * 8 + e) * 256 + col]);
    *reinterpret_cast<bf16x8*>(&pWf2[(size_t)t3 * 8]) = f;
  } else if (tid < 40448) {               // pS: {Wpa2,Wpv2,Ws1} x 2 ks x 4 nt
    int t4 = tid - 38912; int fi = t4 >> 6;
    int mat = fi >> 3, ks = (fi >> 2) & 1, nt = fi & 3;
    const float* W = (mat == 0) ? Wpa2 : (mat == 1) ? Wpv2 : Ws1;
    int col = nt * 16 + c16;
#pragma unroll
    for (int e = 0; e < 8; e++) f[e] = (short)f2bf(W[(ks * 32 + g * 8 + e) * 64 + col]);
    *reinterpret_cast<bf16x8*>(&pS[(size_t)t4 * 8]) = f;
  } else if (tid < 42496) {               // pWo: 2 ks x 16 nt
    int t5 = tid - 40448; int fi = t5 >> 6; int ks = fi >> 4, nt = fi & 15;
    int col = nt * 16 + c16;
#pragma unroll
    for (int e = 0; e < 8; e++) f[e] = (short)f2bf(Wo[(ks * 32 + g * 8 + e) * 256 + col]);
    *reinterpret_cast<bf16x8*>(&pWo[(size_t)t5 * 8]) = f;
  }
}

// ---------------- Kernel 1: LN1 + QKV projection (MFMA, 32 rows / block) ----------------
__global__ __launch_bounds__(256) void k_qkv(
    const float* __restrict__ x, const float* __restrict__ g1, const float* __restrict__ b1,
    const ushort* __restrict__ pW,
    const float* __restrict__ bq, const float* __restrict__ bk, const float* __restrict__ bv,
    float* __restrict__ qo, float* __restrict__ ko, float* __restrict__ vo) {
  __shared__ __align__(16) ushort hs[32 * 256];
  int t = threadIdx.x, lane = t & 63, w = t >> 6;
  size_t row0 = (size_t)blockIdx.x * 32;

  {
    const float4 gv = *reinterpret_cast<const float4*>(&g1[lane * 4]);
    const float4 bvv = *reinterpret_cast<const float4*>(&b1[lane * 4]);
#pragma unroll
    for (int r8 = 0; r8 < 8; r8++) {
      int r = w * 8 + r8;
      const float4 xv = *reinterpret_cast<const float4*>(&x[(row0 + r) * DD + lane * 4]);
      float s = xv.x + xv.y + xv.z + xv.w;
      float s2 = xv.x * xv.x + xv.y * xv.y + xv.z * xv.z + xv.w * xv.w;
      for (int o = 32; o > 0; o >>= 1) { s += __shfl_down(s, o, 64); s2 += __shfl_down(s2, o, 64); }
      s = __shfl(s, 0, 64); s2 = __shfl(s2, 0, 64);
      float m = s * (1.f / DD), rs = rsqrtf(s2 * (1.f / DD) - m * m + 1e-5f);
      u16x4 hv;
      hv[0] = f2bf((xv.x - m) * rs * gv.x + bvv.x);
      hv[1] = f2bf((xv.y - m) * rs * gv.y + bvv.y);
      hv[2] = f2bf((xv.z - m) * rs * gv.z + bvv.z);
      hv[3] = f2bf((xv.w - m) * rs * gv.w + bvv.w);
      int off = (r * 512 + lane * 8) ^ ((r & 7) << 4);
      *reinterpret_cast<u16x4*>(reinterpret_cast<char*>(hs) + off) = hv;
    }
  }
  __syncthreads();

  f32x4 acc[2][3] = {};
  for (int ks = 0; ks < 8; ks++) {
    int rowa = lane & 15, g = lane >> 4;
    bf16x8 a0 = *reinterpret_cast<const bf16x8*>(reinterpret_cast<const char*>(hs) +
                 ((rowa * 512 + ks * 64 + g * 16) ^ ((rowa & 7) << 4)));
    int rowb = rowa + 16;
    bf16x8 a1 = *reinterpret_cast<const bf16x8*>(reinterpret_cast<const char*>(hs) +
                 ((rowb * 512 + ks * 64 + g * 16) ^ ((rowb & 7) << 4)));
#pragma unroll
    for (int j = 0; j < 3; j++) {
      int fi = ks * 12 + w * 3 + j;
      bf16x8 bw = *reinterpret_cast<const bf16x8*>(&pW[((size_t)fi * 64 + lane) * 8]);
      acc[0][j] = __builtin_amdgcn_mfma_f32_16x16x32_bf16(a0, bw, acc[0][j], 0, 0, 0);
      acc[1][j] = __builtin_amdgcn_mfma_f32_16x16x32_bf16(a1, bw, acc[1][j], 0, 0, 0);
    }
  }

#pragma unroll
  for (int j = 0; j < 3; j++) {
    int ntg = w * 3 + j;
    int buf = ntg >> 2;
    float* out = (buf == 0) ? qo : (buf == 1) ? ko : vo;
    const float* bias = (buf == 0) ? bq : (buf == 1) ? bk : bv;
    int col = (ntg & 3) * 16 + (lane & 15);
    float bb = bias[col];
#pragma unroll
    for (int mt = 0; mt < 2; mt++)
#pragma unroll
      for (int r = 0; r < 4; r++) {
        int row = mt * 16 + (lane >> 4) * 4 + r;
        out[(row0 + row) * 64 + col] = acc[mt][j][r] + bb;
      }
  }
}

// ---------------- Kernel 2: attention, 2 points/block, batches fused ----------------
__global__ __launch_bounds__(256) void k_attn(
    const float* __restrict__ x, const float* __restrict__ relpos, const int* __restrict__ knn,
    const float* __restrict__ qg, const float* __restrict__ kg, const float* __restrict__ vg,
    const float* __restrict__ Wpa1, const float* __restrict__ bpa1, const float* __restrict__ bpa2,
    const float* __restrict__ Wpv1, const float* __restrict__ bpv1, const float* __restrict__ bpv2,
    const ushort* __restrict__ pS, const float* __restrict__ bs1,
    const float* __restrict__ Ws2, const float* __restrict__ bs2,
    const ushort* __restrict__ pWo, const float* __restrict__ bo,
    float* __restrict__ xmid) {
  int n0 = blockIdx.x * 2;
  int t = threadIdx.x, lane = t & 63, w = t >> 6;
  int g = lane >> 4, c16 = lane & 15;

  __shared__ __align__(16) ushort A0[64 * 64];    // 8KB: rows 0-31 attn-hidden / tanh tile; rows 32-63 value-hidden
  __shared__ float ra_ls[32][64];                 // 8KB
  __shared__ float rv_ls[32][64];                 // 8KB
  __shared__ __align__(16) ushort ctile[16 * 64]; // 2KB (rows 0-3 = ctx, 4-15 zero)
  __shared__ float qv[4][64];
  __shared__ float scp[64][4];
  __shared__ float attn_s[64];
  __shared__ float rp_s[2][48];
  __shared__ int idx_s[2][16];

  // ---- P0: loads + ctile zero ----
  if (t < 32) idx_s[t >> 4][t & 15] = knn[(n0 + (t >> 4)) * KK + (t & 15)];
  if (t >= 64 && t < 160) {
    int i = t - 64;
    rp_s[i / 48][i % 48] = relpos[(size_t)n0 * 48 + i];
  }
  if (t >= 160 && t < 160 + 192) {
    int i = t - 160;            // 0..191 : zero rows 4-15 of ctile (12 rows x 16 chunks of 8B)
    zstore8(ctile, 4 + (i >> 4), i & 15);
  }
  // qv[mt][col], mt = pt*2 + b  (w plays mt)
  qv[w][lane] = qg[((size_t)(w & 1) * NN + n0 + (w >> 1)) * AA + lane];
  __syncthreads();

  // ---- P1: rel-pos MLP hidden -> A0 (attn rows 0-31, value rows 32-63) ----
  {
    const float* W1 = (w < 2) ? Wpa1 : Wpv1;
    const float* bb1 = (w < 2) ? bpa1 : bpv1;
    float wa0 = W1[lane], wa1 = W1[64 + lane], wa2 = W1[128 + lane], ba = bb1[lane];
    int pt = w & 1;
#pragma unroll
    for (int j = 0; j < 16; j++) {
      float r0 = rp_s[pt][j * 3], r1 = rp_s[pt][j * 3 + 1], r2 = rp_s[pt][j * 3 + 2];
      float v = fmaxf(ba + r0 * wa0 + r1 * wa1 + r2 * wa2, 0.f);
      astore(A0, w * 16 + j, lane, v);
    }
  }
  __syncthreads();

  // ---- P2: ra/rv = hidden @ {Wpa2,Wpv2} + bias (MFMA) ----
  {
    bf16x8 bwa0 = loadfrag(pS, 0 + 0 + w, lane);
    bf16x8 bwa1 = loadfrag(pS, 0 + 4 + w, lane);
    bf16x8 bwv0 = loadfrag(pS, 8 + 0 + w, lane);
    bf16x8 bwv1 = loadfrag(pS, 8 + 4 + w, lane);
    int col = w * 16 + c16;
    float ba2 = bpa2[col], bv2 = bpv2[col];
#pragma unroll
    for (int mt = 0; mt < 2; mt++) {
      bf16x8 a0 = afrag(A0, mt * 16, lane, 0), a1 = afrag(A0, mt * 16, lane, 1);
      f32x4 acc = {0.f, 0.f, 0.f, 0.f};
      acc = __builtin_amdgcn_mfma_f32_16x16x32_bf16(a0, bwa0, acc, 0, 0, 0);
      acc = __builtin_amdgcn_mfma_f32_16x16x32_bf16(a1, bwa1, acc, 0, 0, 0);
#pragma unroll
      for (int r = 0; r < 4; r++) ra_ls[mt * 16 + g * 4 + r][col] = acc[r] + ba2;
      bf16x8 v0 = afrag(A0, 32 + mt * 16, lane, 0), v1 = afrag(A0, 32 + mt * 16, lane, 1);
      f32x4 accv = {0.f, 0.f, 0.f, 0.f};
      accv = __builtin_amdgcn_mfma_f32_16x16x32_bf16(v0, bwv0, accv, 0, 0, 0);
      accv = __builtin_amdgcn_mfma_f32_16x16x32_bf16(v1, bwv1, accv, 0, 0, 0);
#pragma unroll
      for (int r = 0; r < 4; r++) rv_ls[mt * 16 + g * 4 + r][col] = accv[r] + bv2;
    }
  }
  __syncthreads();

  // ---- P3: tanh tile (64 rows = (pt,b,k)), row = w*16+k with mt=w ----
  {
    int pt = w >> 1, b = w & 1;
    float qq = qv[w][lane];
#pragma unroll
    for (int k = 0; k < 16; k++) {
      float kvv = kg[((size_t)b * NN + idx_s[pt][k]) * AA + lane];
      float xx = qq - kvv + ra_ls[pt * 16 + k][lane];
      float ex = __expf(2.f * xx);
      float tv = 1.f - 2.f * __builtin_amdgcn_rcpf(ex + 1.f);
      astore(A0, w * 16 + k, lane, tv);
    }
  }
  __syncthreads();

  // ---- P4: score-hidden MFMA + Ws2 dot + 16-lane reduce ----
  {
    bf16x8 fsA = loadfrag(pS, 16 + 0 + w, lane);
    bf16x8 fsB = loadfrag(pS, 16 + 4 + w, lane);
    int col = w * 16 + c16;
    float bsc = bs1[col], wsc = Ws2[col];
    f32x4 pp[4];
#pragma unroll
    for (int mt = 0; mt < 4; mt++) {
      bf16x8 a0 = afrag(A0, mt * 16, lane, 0), a1 = afrag(A0, mt * 16, lane, 1);
      f32x4 acc = {0.f, 0.f, 0.f, 0.f};
      acc = __builtin_amdgcn_mfma_f32_16x16x32_bf16(a0, fsA, acc, 0, 0, 0);
      acc = __builtin_amdgcn_mfma_f32_16x16x32_bf16(a1, fsB, acc, 0, 0, 0);
#pragma unroll
      for (int r = 0; r < 4; r++) acc[r] = fmaxf(acc[r] + bsc, 0.f) * wsc;
      pp[mt] = acc;
    }
#pragma unroll
    for (int o = 1; o < 16; o <<= 1)
#pragma unroll
      for (int mt = 0; mt < 4; mt++)
#pragma unroll
        for (int r = 0; r < 4; r++) pp[mt][r] += __shfl_xor(pp[mt][r], o, 64);
    if (c16 == 0)
#pragma unroll
      for (int mt = 0; mt < 4; mt++)
#pragma unroll
        for (int r = 0; r < 4; r++) scp[mt * 16 + g * 4 + r][w] = pp[mt][r];
  }
  __syncthreads();

  // ---- P5: softmax over k within each (pt,b) group of 16 ----
  if (t < 64) {
    float4 s4 = *reinterpret_cast<const float4*>(&scp[t][0]);
    float sc = (s4.x + s4.y + s4.z + s4.w + bs2[0]) * 0.125f;
    float mx = sc;
#pragma unroll
    for (int o = 8; o > 0; o >>= 1) mx = fmaxf(mx, __shfl_xor(mx, o, 64));
    float e = __expf(sc - mx);
    float ss = e;
#pragma unroll
    for (int o = 8; o > 0; o >>= 1) ss += __shfl_xor(ss, o, 64);
    attn_s[t] = e / ss;
  }
  __syncthreads();

  // ---- P6: ctx = attn @ (vn + rv), wave w handles mt=w ----
  {
    int pt = w >> 1, b = w & 1;
    float acc = 0.f;
#pragma unroll
    for (int k = 0; k < 16; k++) {
      float vn = vg[((size_t)b * NN + idx_s[pt][k]) * VV + lane] + rv_ls[pt * 16 + k][lane];
      acc += attn_s[w * 16 + k] * vn;
    }
    astore(ctile, w, lane, acc);
  }
  __syncthreads();

  // ---- P7: xmid = x + ctx @ Wo + bo (MFMA, rows 0-3 valid) ----
  {
    bf16x8 a0 = afrag(ctile, 0, lane, 0), a1 = afrag(ctile, 0, lane, 1);
    f32x4 acc[4];
#pragma unroll
    for (int j = 0; j < 4; j++) {
      bf16x8 b0 = loadfrag(pWo, 0 + w * 4 + j, lane);
      bf16x8 b1 = loadfrag(pWo, 16 + w * 4 + j, lane);
      f32x4 a = {0.f, 0.f, 0.f, 0.f};
      a = __builtin_amdgcn_mfma_f32_16x16x32_bf16(a0, b0, a, 0, 0, 0);
      a = __builtin_amdgcn_mfma_f32_16x16x32_bf16(a1, b1, a, 0, 0, 0);
      acc[j] = a;
    }
    if (g == 0) {
#pragma unroll
      for (int j = 0; j < 4; j++) {
        int col = w * 64 + j * 16 + c16;
        float bb = bo[col];
#pragma unroll
        for (int r = 0; r < 4; r++) {   // r = mt = pt*2+b
          int pt = r >> 1, b = r & 1;
          size_t addr = ((size_t)b * NN + n0 + pt) * DD + col;
          xmid[addr] = x[addr] + acc[j][r] + bb;
        }
      }
    }
  }
}

// ---------------- Kernel 3: LN2 + FFN + residual (MFMA, 32 rows / block) ----------------
__global__ __launch_bounds__(256) void k_ffn(
    const float* __restrict__ xmid, const float* __restrict__ g2, const float* __restrict__ b2,
    const ushort* __restrict__ pWf1, const float* __restrict__ bf1,
    const ushort* __restrict__ pWf2, const float* __restrict__ bf2,
    float* __restrict__ out) {
  __shared__ __align__(16) ushort hs[32 * 256];
  __shared__ __align__(16) ushort ys[32 * 512];
  int t = threadIdx.x, lane = t & 63, w = t >> 6;
  size_t row0 = (size_t)blockIdx.x * 32;

  {
    const float4 gv = *reinterpret_cast<const float4*>(&g2[lane * 4]);
    const float4 bvv = *reinterpret_cast<const float4*>(&b2[lane * 4]);
#pragma unroll
    for (int r8 = 0; r8 < 8; r8++) {
      int r = w * 8 + r8;
      const float4 xv = *reinterpret_cast<const float4*>(&xmid[(row0 + r) * DD + lane * 4]);
      float s = xv.x + xv.y + xv.z + xv.w;
      float s2 = xv.x * xv.x + xv.y * xv.y + xv.z * xv.z + xv.w * xv.w;
      for (int o = 32; o > 0; o >>= 1) { s += __shfl_down(s, o, 64); s2 += __shfl_down(s2, o, 64); }
      s = __shfl(s, 0, 64); s2 = __shfl(s2, 0, 64);
      float m = s * (1.f / DD), rs = rsqrtf(s2 * (1.f / DD) - m * m + 1e-5f);
      u16x4 hv;
      hv[0] = f2bf((xv.x - m) * rs * gv.x + bvv.x);
      hv[1] = f2bf((xv.y - m) * rs * gv.y + bvv.y);
      hv[2] = f2bf((xv.z - m) * rs * gv.z + bvv.z);
      hv[3] = f2bf((xv.w - m) * rs * gv.w + bvv.w);
      int off = (r * 512 + lane * 8) ^ ((r & 7) << 4);
      *reinterpret_cast<u16x4*>(reinterpret_cast<char*>(hs) + off) = hv;
    }
  }
  __syncthreads();

  f32x4 acc1[2][8] = {};
  for (int ks = 0; ks < 8; ks++) {
    int rowa = lane & 15, g = lane >> 4;
    bf16x8 a0 = *reinterpret_cast<const bf16x8*>(reinterpret_cast<const char*>(hs) +
                 ((rowa * 512 + ks * 64 + g * 16) ^ ((rowa & 7) << 4)));
    int rowb = rowa + 16;
    bf16x8 a1 = *reinterpret_cast<const bf16x8*>(reinterpret_cast<const char*>(hs) +
                 ((rowb * 512 + ks * 64 + g * 16) ^ ((rowb & 7) << 4)));
#pragma unroll
    for (int j = 0; j < 8; j++) {
      int fi = ks * 32 + w * 8 + j;
      bf16x8 bw = *reinterpret_cast<const bf16x8*>(&pWf1[((size_t)fi * 64 + lane) * 8]);
      acc1[0][j] = __builtin_amdgcn_mfma_f32_16x16x32_bf16(a0, bw, acc1[0][j], 0, 0, 0);
      acc1[1][j] = __builtin_amdgcn_mfma_f32_16x16x32_bf16(a1, bw, acc1[1][j], 0, 0, 0);
    }
  }

#pragma unroll
  for (int j = 0; j < 8; j++) {
    int col = w * 128 + j * 16 + (lane & 15);
    float bb = bf1[col];
#pragma unroll
    for (int mt = 0; mt < 2; mt++)
#pragma unroll
      for (int r = 0; r < 4; r++) {
        float v = acc1[mt][j][r] + bb;
        v = v * 0.5f * (1.f + erff(v * 0.70710678118654752f));
        int row = mt * 16 + (lane >> 4) * 4 + r;
        int off = (row * 1024 + col * 2) ^ ((row & 7) << 4);
        *reinterpret_cast<ushort*>(reinterpret_cast<char*>(ys) + off) = f2bf(v);
      }
  }
  __syncthreads();

  f32x4 acc2[2][4] = {};
  for (int ks = 0; ks < 16; ks++) {
    int rowa = lane & 15, g = lane >> 4;
    bf16x8 a0 = *reinterpret_cast<const bf16x8*>(reinterpret_cast<const char*>(ys) +
                 ((rowa * 1024 + ks * 64 + g * 16) ^ ((rowa & 7) << 4)));
    int rowb = rowa + 16;
    bf16x8 a1 = *reinterpret_cast<const bf16x8*>(reinterpret_cast<const char*>(ys) +
                 ((rowb * 1024 + ks * 64 + g * 16) ^ ((rowb & 7) << 4)));
#pragma unroll
    for (int j = 0; j < 4; j++) {
      int fi = ks * 16 + w * 4 + j;
      bf16x8 bw = *reinterpret_cast<const bf16x8*>(&pWf2[((size_t)fi * 64 + lane) * 8]);
      acc2[0][j] = __builtin_amdgcn_mfma_f32_16x16x32_bf16(a0, bw, acc2[0][j], 0, 0, 0);
      acc2[1][j] = __builtin_amdgcn_mfma_f32_16x16x32_bf16(a1, bw, acc2[1][j], 0, 0, 0);
    }
  }

#pragma unroll
  for (int j = 0; j < 4; j++) {
    int col = w * 64 + j * 16 + (lane & 15);
    float bb = bf2[col];
#pragma unroll
    for (int mt = 0; mt < 2; mt++)
#pragma unroll
      for (int r = 0; r < 4; r++) {
        int row = mt * 16 + (lane >> 4) * 4 + r;
        size_t idx = (row0 + row) * DD + col;
        out[idx] = xmid[idx] + acc2[mt][j][r] + bb;
      }
  }
}

extern "C" void kernel_launch(void* const* d_in, const int* in_sizes, int n_in,
                              void* d_out, int out_size, void* d_ws, size_t ws_size,
                              hipStream_t stream) {
  const float* x      = (const float*)d_in[0];
  const int*   knn    = (const int*)  d_in[1];
  const float* relpos = (const float*)d_in[2];
  const float* g1     = (const float*)d_in[3];
  const float* b1     = (const float*)d_in[4];
  const float* g2     = (const float*)d_in[5];
  const float* b2     = (const float*)d_in[6];
  const float* Wq     = (const float*)d_in[7];
  const float* bq     = (const float*)d_in[8];
  const float* Wk     = (const float*)d_in[9];
  const float* bk     = (const float*)d_in[10];
  const float* Wv     = (const float*)d_in[11];
  const float* bv     = (const float*)d_in[12];
  const float* Wo     = (const float*)d_in[13];
  const float* bo     = (const float*)d_in[14];
  const float* Wpa1   = (const float*)d_in[15];
  const float* bpa1   = (const float*)d_in[16];
  const float* Wpa2   = (const float*)d_in[17];
  const float* bpa2   = (const float*)d_in[18];
  const float* Wpv1   = (const float*)d_in[19];
  const float* bpv1   = (const float*)d_in[20];
  const float* Wpv2   = (const float*)d_in[21];
  const float* bpv2   = (const float*)d_in[22];
  const float* Ws1    = (const float*)d_in[23];
  const float* bs1    = (const float*)d_in[24];
  const float* Ws2    = (const float*)d_in[25];
  const float* bs2    = (const float*)d_in[26];
  const float* Wf1    = (const float*)d_in[27];
  const float* bf1    = (const float*)d_in[28];
  const float* Wf2    = (const float*)d_in[29];
  const float* bf2    = (const float*)d_in[30];

  float* ws   = (float*)d_ws;
  float* q    = ws;
  float* kk   = q  + (size_t)BB * NN * AA;
  float* vv   = kk + (size_t)BB * NN * AA;
  float* xmid = vv + (size_t)BB * NN * VV;
  ushort* pQKV = (ushort*)(xmid + (size_t)BB * NN * DD);
  ushort* pWf1 = pQKV + 49152;
  ushort* pWf2 = pWf1 + 131072;
  ushort* pS   = pWf2 + 131072;
  ushort* pWo  = pS + 12288;

  k_prep<<<166, 256, 0, stream>>>(Wq, Wk, Wv, Wf1, Wf2, Wpa2, Wpv2, Ws1, Wo,
                                  pQKV, pWf1, pWf2, pS, pWo);
  k_qkv<<<(BB * NN) / 32, 256, 0, stream>>>(x, g1, b1, pQKV, bq, bk, bv, q, kk, vv);
  k_attn<<<NN / 2, 256, 0, stream>>>(x, relpos, knn, q, kk, vv,
                                     Wpa1, bpa1, bpa2, Wpv1, bpv1, bpv2,
                                     pS, bs1, Ws2, bs2, pWo, bo, xmid);
  k_ffn<<<(BB * NN) / 32, 256, 0, stream>>>(xmid, g2, b2, pWf1, bf1, pWf2, bf2, (float*)d_out);
}

// Round 6
// 462.430 us; speedup vs baseline: 4.2485x; 1.0254x over previous
//
#include <hip/hip_runtime.h>
#include <hip/hip_bf16.h>
#include <math.h>

#define BB 2
#define NN 32768
#define KK 16
#define DD 256
#define AA 64
#define VV 64

typedef __attribute__((ext_vector_type(8))) short bf16x8;
typedef __attribute__((ext_vector_type(4))) float f32x4;
typedef __attribute__((ext_vector_type(4))) unsigned short u16x4;

__device__ __forceinline__ ushort f2bf(float v) {
  __hip_bfloat16 b = __float2bfloat16(v);
  ushort u; __builtin_memcpy(&u, &b, 2);
  return u;
}
__device__ __forceinline__ float bflo(unsigned u) { return __uint_as_float(u << 16); }
__device__ __forceinline__ float bfhi(unsigned u) { return __uint_as_float(u & 0xffff0000u); }

// swizzled bf16 tile helpers (row stride 128B, XOR swizzle (row&7)<<4)
__device__ __forceinline__ void astore2(ushort* A, int row, int colpair, float lo, float hi) {
  int off = (row * 128 + colpair * 4) ^ ((row & 7) << 4);
  unsigned u = ((unsigned)f2bf(hi) << 16) | (unsigned)f2bf(lo);
  *reinterpret_cast<unsigned*>(reinterpret_cast<char*>(A) + off) = u;
}
__device__ __forceinline__ void zstore8(ushort* A, int row, int chunk) {
  int off = (row * 128 + chunk * 8) ^ ((row & 7) << 4);
  *reinterpret_cast<unsigned long long*>(reinterpret_cast<char*>(A) + off) = 0ULL;
}
__device__ __forceinline__ bf16x8 afrag(const ushort* A, int rowbase, int lane, int ks) {
  int row = rowbase + (lane & 15), g = lane >> 4;
  int off = (row * 128 + ks * 64 + g * 16) ^ ((row & 7) << 4);
  return *reinterpret_cast<const bf16x8*>(reinterpret_cast<const char*>(A) + off);
}
__device__ __forceinline__ bf16x8 loadfrag(const ushort* p, int fi, int lane) {
  return *reinterpret_cast<const bf16x8*>(&p[((size_t)fi * 64 + lane) * 8]);
}

// ---------------- Kernel 0: pack weights into bf16 B-fragment order ----------------
__global__ __launch_bounds__(256) void k_prep(
    const float* __restrict__ Wq, const float* __restrict__ Wk, const float* __restrict__ Wv,
    const float* __restrict__ Wf1, const float* __restrict__ Wf2,
    const float* __restrict__ Wpa2, const float* __restrict__ Wpv2,
    const float* __restrict__ Ws1, const float* __restrict__ Wo,
    ushort* __restrict__ pQKV, ushort* __restrict__ pWf1, ushort* __restrict__ pWf2,
    ushort* __restrict__ pS, ushort* __restrict__ pWo) {
  int tid = blockIdx.x * 256 + threadIdx.x;
  int lane = tid & 63, g = lane >> 4, c16 = lane & 15;
  bf16x8 f;
  if (tid < 6144) {                       // QKV: 8 ks x 12 nt
    int fi = tid >> 6; int ks = fi / 12, nt = fi % 12;
    int col = nt * 16 + c16;
    const float* W = (col < 64) ? Wq : (col < 128) ? Wk : Wv;
    int c = col & 63;
#pragma unroll
    for (int e = 0; e < 8; e++) f[e] = (short)f2bf(W[(ks * 32 + g * 8 + e) * 64 + c]);
    *reinterpret_cast<bf16x8*>(&pQKV[(size_t)tid * 8]) = f;
  } else if (tid < 22528) {               // Wf1: 8 ks x 32 nt
    int t2 = tid - 6144; int fi = t2 >> 6; int ks = fi >> 5, nt = fi & 31;
    int col = nt * 16 + c16;
#pragma unroll
    for (int e = 0; e < 8; e++) f[e] = (short)f2bf(Wf1[(ks * 32 + g * 8 + e) * 512 + col]);
    *reinterpret_cast<bf16x8*>(&pWf1[(size_t)t2 * 8]) = f;
  } else if (tid < 38912) {               // Wf2: 16 ks x 16 nt
    int t3 = tid - 22528; int fi = t3 >> 6; int ks = fi >> 4, nt = fi & 15;
    int col = nt * 16 + c16;
#pragma unroll
    for (int e = 0; e < 8; e++) f[e] = (short)f2bf(Wf2[(ks * 32 + g * 8 + e) * 256 + col]);
    *reinterpret_cast<bf16x8*>(&pWf2[(size_t)t3 * 8]) = f;
  } else if (tid < 40448) {               // pS: {Wpa2,Wpv2,Ws1} x 2 ks x 4 nt
    int t4 = tid - 38912; int fi = t4 >> 6;
    int mat = fi >> 3, ks = (fi >> 2) & 1, nt = fi & 3;
    const float* W = (mat == 0) ? Wpa2 : (mat == 1) ? Wpv2 : Ws1;
    int col = nt * 16 + c16;
#pragma unroll
    for (int e = 0; e < 8; e++) f[e] = (short)f2bf(W[(ks * 32 + g * 8 + e) * 64 + col]);
    *reinterpret_cast<bf16x8*>(&pS[(size_t)t4 * 8]) = f;
  } else if (tid < 42496) {               // pWo: 2 ks x 16 nt
    int t5 = tid - 40448; int fi = t5 >> 6; int ks = fi >> 4, nt = fi & 15;
    int col = nt * 16 + c16;
#pragma unroll
    for (int e = 0; e < 8; e++) f[e] = (short)f2bf(Wo[(ks * 32 + g * 8 + e) * 256 + col]);
    *reinterpret_cast<bf16x8*>(&pWo[(size_t)t5 * 8]) = f;
  }
}

// ---------------- Kernel 1: LN1 + QKV projection (MFMA, bf16 outputs) ----------------
__global__ __launch_bounds__(256) void k_qkv(
    const float* __restrict__ x, const float* __restrict__ g1, const float* __restrict__ b1,
    const ushort* __restrict__ pW,
    const float* __restrict__ bq, const float* __restrict__ bk, const float* __restrict__ bv,
    ushort* __restrict__ qo, ushort* __restrict__ ko, ushort* __restrict__ vo) {
  __shared__ __align__(16) ushort hs[32 * 256];
  int t = threadIdx.x, lane = t & 63, w = t >> 6;
  size_t row0 = (size_t)blockIdx.x * 32;

  {
    const float4 gv = *reinterpret_cast<const float4*>(&g1[lane * 4]);
    const float4 bvv = *reinterpret_cast<const float4*>(&b1[lane * 4]);
#pragma unroll
    for (int r8 = 0; r8 < 8; r8++) {
      int r = w * 8 + r8;
      const float4 xv = *reinterpret_cast<const float4*>(&x[(row0 + r) * DD + lane * 4]);
      float s = xv.x + xv.y + xv.z + xv.w;
      float s2 = xv.x * xv.x + xv.y * xv.y + xv.z * xv.z + xv.w * xv.w;
      for (int o = 32; o > 0; o >>= 1) { s += __shfl_down(s, o, 64); s2 += __shfl_down(s2, o, 64); }
      s = __shfl(s, 0, 64); s2 = __shfl(s2, 0, 64);
      float m = s * (1.f / DD), rs = rsqrtf(s2 * (1.f / DD) - m * m + 1e-5f);
      u16x4 hv;
      hv[0] = f2bf((xv.x - m) * rs * gv.x + bvv.x);
      hv[1] = f2bf((xv.y - m) * rs * gv.y + bvv.y);
      hv[2] = f2bf((xv.z - m) * rs * gv.z + bvv.z);
      hv[3] = f2bf((xv.w - m) * rs * gv.w + bvv.w);
      int off = (r * 512 + lane * 8) ^ ((r & 7) << 4);
      *reinterpret_cast<u16x4*>(reinterpret_cast<char*>(hs) + off) = hv;
    }
  }
  __syncthreads();

  f32x4 acc[2][3] = {};
  for (int ks = 0; ks < 8; ks++) {
    int rowa = lane & 15, g = lane >> 4;
    bf16x8 a0 = *reinterpret_cast<const bf16x8*>(reinterpret_cast<const char*>(hs) +
                 ((rowa * 512 + ks * 64 + g * 16) ^ ((rowa & 7) << 4)));
    int rowb = rowa + 16;
    bf16x8 a1 = *reinterpret_cast<const bf16x8*>(reinterpret_cast<const char*>(hs) +
                 ((rowb * 512 + ks * 64 + g * 16) ^ ((rowb & 7) << 4)));
#pragma unroll
    for (int j = 0; j < 3; j++) {
      int fi = ks * 12 + w * 3 + j;
      bf16x8 bw = *reinterpret_cast<const bf16x8*>(&pW[((size_t)fi * 64 + lane) * 8]);
      acc[0][j] = __builtin_amdgcn_mfma_f32_16x16x32_bf16(a0, bw, acc[0][j], 0, 0, 0);
      acc[1][j] = __builtin_amdgcn_mfma_f32_16x16x32_bf16(a1, bw, acc[1][j], 0, 0, 0);
    }
  }

#pragma unroll
  for (int j = 0; j < 3; j++) {
    int ntg = w * 3 + j;
    int buf = ntg >> 2;
    ushort* out = (buf == 0) ? qo : (buf == 1) ? ko : vo;
    const float* bias = (buf == 0) ? bq : (buf == 1) ? bk : bv;
    int col = (ntg & 3) * 16 + (lane & 15);
    float bb = bias[col];
#pragma unroll
    for (int mt = 0; mt < 2; mt++)
#pragma unroll
      for (int r = 0; r < 4; r++) {
        int row = mt * 16 + (lane >> 4) * 4 + r;
        out[(row0 + row) * 64 + col] = f2bf(acc[mt][j][r] + bb);
      }
  }
}

// ---------------- Kernel 2: attention, 2 points/block, batches fused ----------------
__global__ __launch_bounds__(256) void k_attn(
    const float* __restrict__ x, const float* __restrict__ relpos, const int* __restrict__ knn,
    const ushort* __restrict__ qg, const ushort* __restrict__ kg, const ushort* __restrict__ vg,
    const float* __restrict__ Wpa1, const float* __restrict__ bpa1, const float* __restrict__ bpa2,
    const float* __restrict__ Wpv1, const float* __restrict__ bpv1, const float* __restrict__ bpv2,
    const ushort* __restrict__ pS, const float* __restrict__ bs1,
    const float* __restrict__ Ws2, const float* __restrict__ bs2,
    const ushort* __restrict__ pWo, const float* __restrict__ bo,
    float* __restrict__ xmid) {
  int n0 = blockIdx.x * 2;
  int t = threadIdx.x, lane = t & 63, w = t >> 6;
  int g = lane >> 4, c16 = lane & 15;
  int c2 = lane & 31, kh = lane >> 5;   // column-pair / k-half decomposition

  __shared__ __align__(16) ushort A0[64 * 64];      // 8KB swizzled bf16 tile
  __shared__ __align__(16) ushort ra_bs[32][72];    // 4.5KB bf16
  __shared__ __align__(16) ushort rv_bs[32][72];    // 4.5KB bf16
  __shared__ float hidp[64][68];                    // 17.4KB f32 score partials
  __shared__ __align__(16) ushort ctile[16 * 64];   // 2KB
  __shared__ __align__(8) float qv[4][64];
  __shared__ float attn_s[64];
  __shared__ float rp_s[2][48];
  __shared__ int idx_s[2][16];

  // ---- P0 ----
  if (t < 32) idx_s[t >> 4][t & 15] = knn[(n0 + (t >> 4)) * KK + (t & 15)];
  if (t >= 64 && t < 160) {
    int i = t - 64;
    rp_s[i / 48][i % 48] = relpos[(size_t)n0 * 48 + i];
  }
  if (t >= 160 && t < 160 + 192) {
    int i = t - 160;
    zstore8(ctile, 4 + (i >> 4), i & 15);
  }
  qv[w][lane] = bflo(qg[((size_t)(w & 1) * NN + n0 + (w >> 1)) * AA + lane]);
  __syncthreads();

  // ---- P1: rel-pos MLP hidden (2 cols x 8 rows per thread) ----
  {
    const float* W1 = (w < 2) ? Wpa1 : Wpv1;
    const float* bb1 = (w < 2) ? bpa1 : bpv1;
    int pt = w & 1;
    int base = (w < 2 ? 0 : 32) + pt * 16;
    float2 w0 = *reinterpret_cast<const float2*>(&W1[2 * c2]);
    float2 w1 = *reinterpret_cast<const float2*>(&W1[64 + 2 * c2]);
    float2 w2 = *reinterpret_cast<const float2*>(&W1[128 + 2 * c2]);
    float2 bb = *reinterpret_cast<const float2*>(&bb1[2 * c2]);
#pragma unroll
    for (int j = 0; j < 8; j++) {
      int k = kh * 8 + j;
      float r0 = rp_s[pt][k * 3], r1 = rp_s[pt][k * 3 + 1], r2 = rp_s[pt][k * 3 + 2];
      float lo = fmaxf(bb.x + r0 * w0.x + r1 * w1.x + r2 * w2.x, 0.f);
      float hi = fmaxf(bb.y + r0 * w0.y + r1 * w1.y + r2 * w2.y, 0.f);
      astore2(A0, base + k, c2, lo, hi);
    }
  }
  __syncthreads();

  // ---- P2: ra/rv = hidden @ {Wpa2,Wpv2} + bias (MFMA) -> bf16 LDS ----
  {
    bf16x8 bwa0 = loadfrag(pS, 0 + w, lane);
    bf16x8 bwa1 = loadfrag(pS, 4 + w, lane);
    bf16x8 bwv0 = loadfrag(pS, 8 + w, lane);
    bf16x8 bwv1 = loadfrag(pS, 12 + w, lane);
    int col = w * 16 + c16;
    float ba2 = bpa2[col], bv2 = bpv2[col];
#pragma unroll
    for (int mt = 0; mt < 2; mt++) {
      bf16x8 a0 = afrag(A0, mt * 16, lane, 0), a1 = afrag(A0, mt * 16, lane, 1);
      f32x4 acc = {0.f, 0.f, 0.f, 0.f};
      acc = __builtin_amdgcn_mfma_f32_16x16x32_bf16(a0, bwa0, acc, 0, 0, 0);
      acc = __builtin_amdgcn_mfma_f32_16x16x32_bf16(a1, bwa1, acc, 0, 0, 0);
#pragma unroll
      for (int r = 0; r < 4; r++) ra_bs[mt * 16 + g * 4 + r][col] = f2bf(acc[r] + ba2);
      bf16x8 v0 = afrag(A0, 32 + mt * 16, lane, 0), v1 = afrag(A0, 32 + mt * 16, lane, 1);
      f32x4 accv = {0.f, 0.f, 0.f, 0.f};
      accv = __builtin_amdgcn_mfma_f32_16x16x32_bf16(v0, bwv0, accv, 0, 0, 0);
      accv = __builtin_amdgcn_mfma_f32_16x16x32_bf16(v1, bwv1, accv, 0, 0, 0);
#pragma unroll
      for (int r = 0; r < 4; r++) rv_bs[mt * 16 + g * 4 + r][col] = f2bf(accv[r] + bv2);
    }
  }
  __syncthreads();

  // ---- P3: tanh tile (2 cols x 8 k per thread) ----
  {
    int pt = w >> 1, b = w & 1;
    float2 qq = *reinterpret_cast<const float2*>(&qv[w][2 * c2]);
    size_t bbase = (size_t)b * NN;
#pragma unroll
    for (int j = 0; j < 8; j++) {
      int k = kh * 8 + j;
      const ushort* krow = kg + (bbase + idx_s[pt][k]) * AA;
      unsigned ku = *reinterpret_cast<const unsigned*>(&krow[2 * c2]);
      unsigned ru = *reinterpret_cast<const unsigned*>(&ra_bs[pt * 16 + k][2 * c2]);
      float x0 = qq.x - bflo(ku) + bflo(ru);
      float x1 = qq.y - bfhi(ku) + bfhi(ru);
      float t0 = 1.f - 2.f * __builtin_amdgcn_rcpf(__expf(2.f * x0) + 1.f);
      float t1 = 1.f - 2.f * __builtin_amdgcn_rcpf(__expf(2.f * x1) + 1.f);
      astore2(A0, w * 16 + k, c2, t0, t1);
    }
  }
  __syncthreads();

  // ---- P4: score-hidden MFMA; relu * Ws2[col] -> hidp ----
  {
    bf16x8 fsA = loadfrag(pS, 16 + w, lane);
    bf16x8 fsB = loadfrag(pS, 20 + w, lane);
    int col = w * 16 + c16;
    float bsc = bs1[col], wsc = Ws2[col];
#pragma unroll
    for (int mt = 0; mt < 4; mt++) {
      bf16x8 a0 = afrag(A0, mt * 16, lane, 0), a1 = afrag(A0, mt * 16, lane, 1);
      f32x4 acc = {0.f, 0.f, 0.f, 0.f};
      acc = __builtin_amdgcn_mfma_f32_16x16x32_bf16(a0, fsA, acc, 0, 0, 0);
      acc = __builtin_amdgcn_mfma_f32_16x16x32_bf16(a1, fsB, acc, 0, 0, 0);
#pragma unroll
      for (int r = 0; r < 4; r++)
        hidp[mt * 16 + g * 4 + r][col] = fmaxf(acc[r] + bsc, 0.f) * wsc;
    }
  }
  __syncthreads();

  // ---- P5: row-sum + softmax over each 16-row group ----
  if (t < 64) {
    float s = 0.f;
#pragma unroll
    for (int c = 0; c < 16; c++) {
      float4 v4 = *reinterpret_cast<const float4*>(&hidp[t][c * 4]);
      s += v4.x + v4.y + v4.z + v4.w;
    }
    float sc = (s + bs2[0]) * 0.125f;
    float mx = sc;
#pragma unroll
    for (int o = 8; o > 0; o >>= 1) mx = fmaxf(mx, __shfl_xor(mx, o, 64));
    float e = __expf(sc - mx);
    float ss = e;
#pragma unroll
    for (int o = 8; o > 0; o >>= 1) ss += __shfl_xor(ss, o, 64);
    attn_s[t] = e / ss;
  }
  __syncthreads();

  // ---- P6: ctx = attn @ (vn + rv) (2 cols x 8 k + cross-half reduce) ----
  {
    int pt = w >> 1, b = w & 1;
    size_t bbase = (size_t)b * NN;
    float a0 = 0.f, a1 = 0.f;
#pragma unroll
    for (int j = 0; j < 8; j++) {
      int k = kh * 8 + j;
      const ushort* vrow = vg + (bbase + idx_s[pt][k]) * VV;
      unsigned vu = *reinterpret_cast<const unsigned*>(&vrow[2 * c2]);
      unsigned ru = *reinterpret_cast<const unsigned*>(&rv_bs[pt * 16 + k][2 * c2]);
      float aw = attn_s[w * 16 + k];
      a0 += aw * (bflo(vu) + bflo(ru));
      a1 += aw * (bfhi(vu) + bfhi(ru));
    }
    a0 += __shfl_xor(a0, 32, 64);
    a1 += __shfl_xor(a1, 32, 64);
    if (kh == 0) astore2(ctile, w, c2, a0, a1);
  }
  __syncthreads();

  // ---- P7: xmid = x + ctx @ Wo + bo (MFMA) ----
  {
    bf16x8 a0 = afrag(ctile, 0, lane, 0), a1 = afrag(ctile, 0, lane, 1);
    f32x4 acc[4];
#pragma unroll
    for (int j = 0; j < 4; j++) {
      bf16x8 b0 = loadfrag(pWo, 0 + w * 4 + j, lane);
      bf16x8 b1 = loadfrag(pWo, 16 + w * 4 + j, lane);
      f32x4 a = {0.f, 0.f, 0.f, 0.f};
      a = __builtin_amdgcn_mfma_f32_16x16x32_bf16(a0, b0, a, 0, 0, 0);
      a = __builtin_amdgcn_mfma_f32_16x16x32_bf16(a1, b1, a, 0, 0, 0);
      acc[j] = a;
    }
    if (g == 0) {
#pragma unroll
      for (int j = 0; j < 4; j++) {
        int col = w * 64 + j * 16 + c16;
        float bb = bo[col];
#pragma unroll
        for (int r = 0; r < 4; r++) {   // r = mt = pt*2+b
          int pt = r >> 1, b = r & 1;
          size_t addr = ((size_t)b * NN + n0 + pt) * DD + col;
          xmid[addr] = x[addr] + acc[j][r] + bb;
        }
      }
    }
  }
}

// ---------------- Kernel 3: LN2 + FFN + residual (MFMA, 32 rows / block) ----------------
__global__ __launch_bounds__(256) void k_ffn(
    const float* __restrict__ xmid, const float* __restrict__ g2, const float* __restrict__ b2,
    const ushort* __restrict__ pWf1, const float* __restrict__ bf1,
    const ushort* __restrict__ pWf2, const float* __restrict__ bf2,
    float* __restrict__ out) {
  __shared__ __align__(16) ushort hs[32 * 256];
  __shared__ __align__(16) ushort ys[32 * 512];
  int t = threadIdx.x, lane = t & 63, w = t >> 6;
  size_t row0 = (size_t)blockIdx.x * 32;

  {
    const float4 gv = *reinterpret_cast<const float4*>(&g2[lane * 4]);
    const float4 bvv = *reinterpret_cast<const float4*>(&b2[lane * 4]);
#pragma unroll
    for (int r8 = 0; r8 < 8; r8++) {
      int r = w * 8 + r8;
      const float4 xv = *reinterpret_cast<const float4*>(&xmid[(row0 + r) * DD + lane * 4]);
      float s = xv.x + xv.y + xv.z + xv.w;
      float s2 = xv.x * xv.x + xv.y * xv.y + xv.z * xv.z + xv.w * xv.w;
      for (int o = 32; o > 0; o >>= 1) { s += __shfl_down(s, o, 64); s2 += __shfl_down(s2, o, 64); }
      s = __shfl(s, 0, 64); s2 = __shfl(s2, 0, 64);
      float m = s * (1.f / DD), rs = rsqrtf(s2 * (1.f / DD) - m * m + 1e-5f);
      u16x4 hv;
      hv[0] = f2bf((xv.x - m) * rs * gv.x + bvv.x);
      hv[1] = f2bf((xv.y - m) * rs * gv.y + bvv.y);
      hv[2] = f2bf((xv.z - m) * rs * gv.z + bvv.z);
      hv[3] = f2bf((xv.w - m) * rs * gv.w + bvv.w);
      int off = (r * 512 + lane * 8) ^ ((r & 7) << 4);
      *reinterpret_cast<u16x4*>(reinterpret_cast<char*>(hs) + off) = hv;
    }
  }
  __syncthreads();

  f32x4 acc1[2][8] = {};
  for (int ks = 0; ks < 8; ks++) {
    int rowa = lane & 15, g = lane >> 4;
    bf16x8 a0 = *reinterpret_cast<const bf16x8*>(reinterpret_cast<const char*>(hs) +
                 ((rowa * 512 + ks * 64 + g * 16) ^ ((rowa & 7) << 4)));
    int rowb = rowa + 16;
    bf16x8 a1 = *reinterpret_cast<const bf16x8*>(reinterpret_cast<const char*>(hs) +
                 ((rowb * 512 + ks * 64 + g * 16) ^ ((rowb & 7) << 4)));
#pragma unroll
    for (int j = 0; j < 8; j++) {
      int fi = ks * 32 + w * 8 + j;
      bf16x8 bw = *reinterpret_cast<const bf16x8*>(&pWf1[((size_t)fi * 64 + lane) * 8]);
      acc1[0][j] = __builtin_amdgcn_mfma_f32_16x16x32_bf16(a0, bw, acc1[0][j], 0, 0, 0);
      acc1[1][j] = __builtin_amdgcn_mfma_f32_16x16x32_bf16(a1, bw, acc1[1][j], 0, 0, 0);
    }
  }

#pragma unroll
  for (int j = 0; j < 8; j++) {
    int col = w * 128 + j * 16 + (lane & 15);
    float bb = bf1[col];
#pragma unroll
    for (int mt = 0; mt < 2; mt++)
#pragma unroll
      for (int r = 0; r < 4; r++) {
        float v = acc1[mt][j][r] + bb;
        v = v * 0.5f * (1.f + erff(v * 0.70710678118654752f));
        int row = mt * 16 + (lane >> 4) * 4 + r;
        int off = (row * 1024 + col * 2) ^ ((row & 7) << 4);
        *reinterpret_cast<ushort*>(reinterpret_cast<char*>(ys) + off) = f2bf(v);
      }
  }
  __syncthreads();

  f32x4 acc2[2][4] = {};
  for (int ks = 0; ks < 16; ks++) {
    int rowa = lane & 15, g = lane >> 4;
    bf16x8 a0 = *reinterpret_cast<const bf16x8*>(reinterpret_cast<const char*>(ys) +
                 ((rowa * 1024 + ks * 64 + g * 16) ^ ((rowa & 7) << 4)));
    int rowb = rowa + 16;
    bf16x8 a1 = *reinterpret_cast<const bf16x8*>(reinterpret_cast<const char*>(ys) +
                 ((rowb * 1024 + ks * 64 + g * 16) ^ ((rowb & 7) << 4)));
#pragma unroll
    for (int j = 0; j < 4; j++) {
      int fi = ks * 16 + w * 4 + j;
      bf16x8 bw = *reinterpret_cast<const bf16x8*>(&pWf2[((size_t)fi * 64 + lane) * 8]);
      acc2[0][j] = __builtin_amdgcn_mfma_f32_16x16x32_bf16(a0, bw, acc2[0][j], 0, 0, 0);
      acc2[1][j] = __builtin_amdgcn_mfma_f32_16x16x32_bf16(a1, bw, acc2[1][j], 0, 0, 0);
    }
  }

#pragma unroll
  for (int j = 0; j < 4; j++) {
    int col = w * 64 + j * 16 + (lane & 15);
    float bb = bf2[col];
#pragma unroll
    for (int mt = 0; mt < 2; mt++)
#pragma unroll
      for (int r = 0; r < 4; r++) {
        int row = mt * 16 + (lane >> 4) * 4 + r;
        size_t idx = (row0 + row) * DD + col;
        out[idx] = xmid[idx] + acc2[mt][j][r] + bb;
      }
  }
}

extern "C" void kernel_launch(void* const* d_in, const int* in_sizes, int n_in,
                              void* d_out, int out_size, void* d_ws, size_t ws_size,
                              hipStream_t stream) {
  const float* x      = (const float*)d_in[0];
  const int*   knn    = (const int*)  d_in[1];
  const float* relpos = (const float*)d_in[2];
  const float* g1     = (const float*)d_in[3];
  const float* b1     = (const float*)d_in[4];
  const float* g2     = (const float*)d_in[5];
  const float* b2     = (const float*)d_in[6];
  const float* Wq     = (const float*)d_in[7];
  const float* bq     = (const float*)d_in[8];
  const float* Wk     = (const float*)d_in[9];
  const float* bk     = (const float*)d_in[10];
  const float* Wv     = (const float*)d_in[11];
  const float* bv     = (const float*)d_in[12];
  const float* Wo     = (const float*)d_in[13];
  const float* bo     = (const float*)d_in[14];
  const float* Wpa1   = (const float*)d_in[15];
  const float* bpa1   = (const float*)d_in[16];
  const float* Wpa2   = (const float*)d_in[17];
  const float* bpa2   = (const float*)d_in[18];
  const float* Wpv1   = (const float*)d_in[19];
  const float* bpv1   = (const float*)d_in[20];
  const float* Wpv2   = (const float*)d_in[21];
  const float* bpv2   = (const float*)d_in[22];
  const float* Ws1    = (const float*)d_in[23];
  const float* bs1    = (const float*)d_in[24];
  const float* Ws2    = (const float*)d_in[25];
  const float* bs2    = (const float*)d_in[26];
  const float* Wf1    = (const float*)d_in[27];
  const float* bf1    = (const float*)d_in[28];
  const float* Wf2    = (const float*)d_in[29];
  const float* bf2    = (const float*)d_in[30];

  ushort* qb = (ushort*)d_ws;                       // 3 x 8MB bf16 q/k/v
  ushort* kb = qb + (size_t)BB * NN * AA;
  ushort* vb = kb + (size_t)BB * NN * AA;
  float* xmid = (float*)(vb + (size_t)BB * NN * VV);
  ushort* pQKV = (ushort*)(xmid + (size_t)BB * NN * DD);
  ushort* pWf1 = pQKV + 49152;
  ushort* pWf2 = pWf1 + 131072;
  ushort* pS   = pWf2 + 131072;
  ushort* pWo  = pS + 12288;

  k_prep<<<166, 256, 0, stream>>>(Wq, Wk, Wv, Wf1, Wf2, Wpa2, Wpv2, Ws1, Wo,
                                  pQKV, pWf1, pWf2, pS, pWo);
  k_qkv<<<(BB * NN) / 32, 256, 0, stream>>>(x, g1, b1, pQKV, bq, bk, bv, qb, kb, vb);
  k_attn<<<NN / 2, 256, 0, stream>>>(x, relpos, knn, qb, kb, vb,
                                     Wpa1, bpa1, bpa2, Wpv1, bpv1, bpv2,
                                     pS, bs1, Ws2, bs2, pWo, bo, xmid);
  k_ffn<<<(BB * NN) / 32, 256, 0, stream>>>(xmid, g2, b2, pWf1, bf1, pWf2, bf2, (float*)d_out);
}

// Round 7
// 423.338 us; speedup vs baseline: 4.6408x; 1.0923x over previous
//
#include <hip/hip_runtime.h>
#include <hip/hip_bf16.h>
#include <math.h>

#define BB 2
#define NN 32768
#define KK 16
#define DD 256
#define AA 64
#define VV 64

typedef __attribute__((ext_vector_type(8))) short bf16x8;
typedef __attribute__((ext_vector_type(4))) float f32x4;
typedef __attribute__((ext_vector_type(4))) unsigned short u16x4;

__device__ __forceinline__ ushort f2bf(float v) {
  __hip_bfloat16 b = __float2bfloat16(v);
  ushort u; __builtin_memcpy(&u, &b, 2);
  return u;
}
__device__ __forceinline__ float bflo(unsigned u) { return __uint_as_float(u << 16); }
__device__ __forceinline__ float bfhi(unsigned u) { return __uint_as_float(u & 0xffff0000u); }

// swizzled bf16 tile helpers (row stride 128B, XOR swizzle (row&7)<<4)
__device__ __forceinline__ void astore2(ushort* A, int row, int colpair, float lo, float hi) {
  int off = (row * 128 + colpair * 4) ^ ((row & 7) << 4);
  unsigned u = ((unsigned)f2bf(hi) << 16) | (unsigned)f2bf(lo);
  *reinterpret_cast<unsigned*>(reinterpret_cast<char*>(A) + off) = u;
}
__device__ __forceinline__ void zstore8(ushort* A, int row, int chunk) {
  int off = (row * 128 + chunk * 8) ^ ((row & 7) << 4);
  *reinterpret_cast<unsigned long long*>(reinterpret_cast<char*>(A) + off) = 0ULL;
}
__device__ __forceinline__ bf16x8 afrag(const ushort* A, int rowbase, int lane, int ks) {
  int row = rowbase + (lane & 15), g = lane >> 4;
  int off = (row * 128 + ks * 64 + g * 16) ^ ((row & 7) << 4);
  return *reinterpret_cast<const bf16x8*>(reinterpret_cast<const char*>(A) + off);
}
__device__ __forceinline__ bf16x8 loadfrag(const ushort* p, int fi, int lane) {
  return *reinterpret_cast<const bf16x8*>(&p[((size_t)fi * 64 + lane) * 8]);
}

// ---------------- Kernel 0: pack weights into bf16 B-fragment order ----------------
__global__ __launch_bounds__(256) void k_prep(
    const float* __restrict__ Wq, const float* __restrict__ Wk, const float* __restrict__ Wv,
    const float* __restrict__ Wf1, const float* __restrict__ Wf2,
    const float* __restrict__ Wpa2, const float* __restrict__ Wpv2,
    const float* __restrict__ Ws1, const float* __restrict__ Wo,
    ushort* __restrict__ pQKV, ushort* __restrict__ pWf1, ushort* __restrict__ pWf2,
    ushort* __restrict__ pS, ushort* __restrict__ pWo) {
  int tid = blockIdx.x * 256 + threadIdx.x;
  int lane = tid & 63, g = lane >> 4, c16 = lane & 15;
  bf16x8 f;
  if (tid < 6144) {                       // QKV: 8 ks x 12 nt
    int fi = tid >> 6; int ks = fi / 12, nt = fi % 12;
    int col = nt * 16 + c16;
    const float* W = (col < 64) ? Wq : (col < 128) ? Wk : Wv;
    int c = col & 63;
#pragma unroll
    for (int e = 0; e < 8; e++) f[e] = (short)f2bf(W[(ks * 32 + g * 8 + e) * 64 + c]);
    *reinterpret_cast<bf16x8*>(&pQKV[(size_t)tid * 8]) = f;
  } else if (tid < 22528) {               // Wf1: 8 ks x 32 nt
    int t2 = tid - 6144; int fi = t2 >> 6; int ks = fi >> 5, nt = fi & 31;
    int col = nt * 16 + c16;
#pragma unroll
    for (int e = 0; e < 8; e++) f[e] = (short)f2bf(Wf1[(ks * 32 + g * 8 + e) * 512 + col]);
    *reinterpret_cast<bf16x8*>(&pWf1[(size_t)t2 * 8]) = f;
  } else if (tid < 38912) {               // Wf2: 16 ks x 16 nt
    int t3 = tid - 22528; int fi = t3 >> 6; int ks = fi >> 4, nt = fi & 15;
    int col = nt * 16 + c16;
#pragma unroll
    for (int e = 0; e < 8; e++) f[e] = (short)f2bf(Wf2[(ks * 32 + g * 8 + e) * 256 + col]);
    *reinterpret_cast<bf16x8*>(&pWf2[(size_t)t3 * 8]) = f;
  } else if (tid < 40448) {               // pS: {Wpa2,Wpv2,Ws1} x 2 ks x 4 nt
    int t4 = tid - 38912; int fi = t4 >> 6;
    int mat = fi >> 3, ks = (fi >> 2) & 1, nt = fi & 3;
    const float* W = (mat == 0) ? Wpa2 : (mat == 1) ? Wpv2 : Ws1;
    int col = nt * 16 + c16;
#pragma unroll
    for (int e = 0; e < 8; e++) f[e] = (short)f2bf(W[(ks * 32 + g * 8 + e) * 64 + col]);
    *reinterpret_cast<bf16x8*>(&pS[(size_t)t4 * 8]) = f;
  } else if (tid < 42496) {               // pWo: 2 ks x 16 nt
    int t5 = tid - 40448; int fi = t5 >> 6; int ks = fi >> 4, nt = fi & 15;
    int col = nt * 16 + c16;
#pragma unroll
    for (int e = 0; e < 8; e++) f[e] = (short)f2bf(Wo[(ks * 32 + g * 8 + e) * 256 + col]);
    *reinterpret_cast<bf16x8*>(&pWo[(size_t)t5 * 8]) = f;
  }
}

// ---------------- Kernel 1: LN1 + QKV projection (MFMA, bf16 outputs, prefetched) ----------------
__global__ __launch_bounds__(256) void k_qkv(
    const float* __restrict__ x, const float* __restrict__ g1, const float* __restrict__ b1,
    const ushort* __restrict__ pW,
    const float* __restrict__ bq, const float* __restrict__ bk, const float* __restrict__ bv,
    ushort* __restrict__ qo, ushort* __restrict__ ko, ushort* __restrict__ vo) {
  __shared__ __align__(16) ushort hs[32 * 256];
  int t = threadIdx.x, lane = t & 63, w = t >> 6;
  size_t row0 = (size_t)blockIdx.x * 32;

  {
    const float4 gv = *reinterpret_cast<const float4*>(&g1[lane * 4]);
    const float4 bvv = *reinterpret_cast<const float4*>(&b1[lane * 4]);
#pragma unroll
    for (int r8 = 0; r8 < 8; r8++) {
      int r = w * 8 + r8;
      const float4 xv = *reinterpret_cast<const float4*>(&x[(row0 + r) * DD + lane * 4]);
      float s = xv.x + xv.y + xv.z + xv.w;
      float s2 = xv.x * xv.x + xv.y * xv.y + xv.z * xv.z + xv.w * xv.w;
      for (int o = 32; o > 0; o >>= 1) { s += __shfl_down(s, o, 64); s2 += __shfl_down(s2, o, 64); }
      s = __shfl(s, 0, 64); s2 = __shfl(s2, 0, 64);
      float m = s * (1.f / DD), rs = rsqrtf(s2 * (1.f / DD) - m * m + 1e-5f);
      u16x4 hv;
      hv[0] = f2bf((xv.x - m) * rs * gv.x + bvv.x);
      hv[1] = f2bf((xv.y - m) * rs * gv.y + bvv.y);
      hv[2] = f2bf((xv.z - m) * rs * gv.z + bvv.z);
      hv[3] = f2bf((xv.w - m) * rs * gv.w + bvv.w);
      int off = (r * 512 + lane * 8) ^ ((r & 7) << 4);
      *reinterpret_cast<u16x4*>(reinterpret_cast<char*>(hs) + off) = hv;
    }
  }
  __syncthreads();

  // GEMM with depth-2 rotating weight prefetch (all indices static after unroll)
  f32x4 acc[2][3] = {};
  bf16x8 fw[3][3];
  int rowa = lane & 15, gg = lane >> 4;
#pragma unroll
  for (int p = 0; p < 2; p++)
#pragma unroll
    for (int j = 0; j < 3; j++) fw[p][j] = loadfrag(pW, p * 12 + w * 3 + j, lane);
#pragma unroll
  for (int ks = 0; ks < 8; ks++) {
    if (ks + 2 < 8) {
#pragma unroll
      for (int j = 0; j < 3; j++) fw[(ks + 2) % 3][j] = loadfrag(pW, (ks + 2) * 12 + w * 3 + j, lane);
    }
    bf16x8 a0 = *reinterpret_cast<const bf16x8*>(reinterpret_cast<const char*>(hs) +
                 ((rowa * 512 + ks * 64 + gg * 16) ^ ((rowa & 7) << 4)));
    bf16x8 a1 = *reinterpret_cast<const bf16x8*>(reinterpret_cast<const char*>(hs) +
                 (((rowa + 16) * 512 + ks * 64 + gg * 16) ^ ((rowa & 7) << 4)));
#pragma unroll
    for (int j = 0; j < 3; j++) {
      acc[0][j] = __builtin_amdgcn_mfma_f32_16x16x32_bf16(a0, fw[ks % 3][j], acc[0][j], 0, 0, 0);
      acc[1][j] = __builtin_amdgcn_mfma_f32_16x16x32_bf16(a1, fw[ks % 3][j], acc[1][j], 0, 0, 0);
    }
  }

#pragma unroll
  for (int j = 0; j < 3; j++) {
    int ntg = w * 3 + j;
    int buf = ntg >> 2;
    ushort* out = (buf == 0) ? qo : (buf == 1) ? ko : vo;
    const float* bias = (buf == 0) ? bq : (buf == 1) ? bk : bv;
    int col = (ntg & 3) * 16 + (lane & 15);
    float bb = bias[col];
#pragma unroll
    for (int mt = 0; mt < 2; mt++)
#pragma unroll
      for (int r = 0; r < 4; r++) {
        int row = mt * 16 + (lane >> 4) * 4 + r;
        out[(row0 + row) * 64 + col] = f2bf(acc[mt][j][r] + bb);
      }
  }
}

// ---------------- Kernel 2: attention, 2 points/block, batches fused ----------------
__global__ __launch_bounds__(256) void k_attn(
    const float* __restrict__ x, const float* __restrict__ relpos, const int* __restrict__ knn,
    const ushort* __restrict__ qg, const ushort* __restrict__ kg, const ushort* __restrict__ vg,
    const float* __restrict__ Wpa1, const float* __restrict__ bpa1, const float* __restrict__ bpa2,
    const float* __restrict__ Wpv1, const float* __restrict__ bpv1, const float* __restrict__ bpv2,
    const ushort* __restrict__ pS, const float* __restrict__ bs1,
    const float* __restrict__ Ws2, const float* __restrict__ bs2,
    const ushort* __restrict__ pWo, const float* __restrict__ bo,
    float* __restrict__ xmid) {
  int n0 = blockIdx.x * 2;
  int t = threadIdx.x, lane = t & 63, w = t >> 6;
  int g = lane >> 4, c16 = lane & 15;
  int c2 = lane & 31, kh = lane >> 5;   // column-pair / k-half decomposition

  __shared__ __align__(16) ushort A0[64 * 64];      // 8KB swizzled bf16 tile
  __shared__ __align__(16) ushort ra_bs[32][72];    // 4.5KB bf16
  __shared__ __align__(16) ushort rv_bs[32][72];    // 4.5KB bf16
  __shared__ float hidp[64][68];                    // 17.4KB f32 score partials
  __shared__ __align__(16) ushort ctile[16 * 64];   // 2KB
  __shared__ __align__(8) float qv[4][64];
  __shared__ float attn_s[64];
  __shared__ float rp_s[2][48];
  __shared__ int idx_s[2][16];

  // ---- P0 ----
  if (t < 32) idx_s[t >> 4][t & 15] = knn[(n0 + (t >> 4)) * KK + (t & 15)];
  if (t >= 64 && t < 160) {
    int i = t - 64;
    rp_s[i / 48][i % 48] = relpos[(size_t)n0 * 48 + i];
  }
  if (t >= 160 && t < 160 + 192) {
    int i = t - 160;
    zstore8(ctile, 4 + (i >> 4), i & 15);
  }
  qv[w][lane] = bflo(qg[((size_t)(w & 1) * NN + n0 + (w >> 1)) * AA + lane]);
  __syncthreads();

  // ---- P1: rel-pos MLP hidden (2 cols x 8 rows per thread) ----
  {
    const float* W1 = (w < 2) ? Wpa1 : Wpv1;
    const float* bb1 = (w < 2) ? bpa1 : bpv1;
    int pt = w & 1;
    int base = (w < 2 ? 0 : 32) + pt * 16;
    float2 w0 = *reinterpret_cast<const float2*>(&W1[2 * c2]);
    float2 w1 = *reinterpret_cast<const float2*>(&W1[64 + 2 * c2]);
    float2 w2 = *reinterpret_cast<const float2*>(&W1[128 + 2 * c2]);
    float2 bb = *reinterpret_cast<const float2*>(&bb1[2 * c2]);
#pragma unroll
    for (int j = 0; j < 8; j++) {
      int k = kh * 8 + j;
      float r0 = rp_s[pt][k * 3], r1 = rp_s[pt][k * 3 + 1], r2 = rp_s[pt][k * 3 + 2];
      float lo = fmaxf(bb.x + r0 * w0.x + r1 * w1.x + r2 * w2.x, 0.f);
      float hi = fmaxf(bb.y + r0 * w0.y + r1 * w1.y + r2 * w2.y, 0.f);
      astore2(A0, base + k, c2, lo, hi);
    }
  }
  __syncthreads();

  // ---- P2: ra/rv = hidden @ {Wpa2,Wpv2} + bias (MFMA) -> bf16 LDS ----
  {
    bf16x8 bwa0 = loadfrag(pS, 0 + w, lane);
    bf16x8 bwa1 = loadfrag(pS, 4 + w, lane);
    bf16x8 bwv0 = loadfrag(pS, 8 + w, lane);
    bf16x8 bwv1 = loadfrag(pS, 12 + w, lane);
    int col = w * 16 + c16;
    float ba2 = bpa2[col], bv2 = bpv2[col];
#pragma unroll
    for (int mt = 0; mt < 2; mt++) {
      bf16x8 a0 = afrag(A0, mt * 16, lane, 0), a1 = afrag(A0, mt * 16, lane, 1);
      f32x4 acc = {0.f, 0.f, 0.f, 0.f};
      acc = __builtin_amdgcn_mfma_f32_16x16x32_bf16(a0, bwa0, acc, 0, 0, 0);
      acc = __builtin_amdgcn_mfma_f32_16x16x32_bf16(a1, bwa1, acc, 0, 0, 0);
#pragma unroll
      for (int r = 0; r < 4; r++) ra_bs[mt * 16 + g * 4 + r][col] = f2bf(acc[r] + ba2);
      bf16x8 v0 = afrag(A0, 32 + mt * 16, lane, 0), v1 = afrag(A0, 32 + mt * 16, lane, 1);
      f32x4 accv = {0.f, 0.f, 0.f, 0.f};
      accv = __builtin_amdgcn_mfma_f32_16x16x32_bf16(v0, bwv0, accv, 0, 0, 0);
      accv = __builtin_amdgcn_mfma_f32_16x16x32_bf16(v1, bwv1, accv, 0, 0, 0);
#pragma unroll
      for (int r = 0; r < 4; r++) rv_bs[mt * 16 + g * 4 + r][col] = f2bf(accv[r] + bv2);
    }
  }
  __syncthreads();

  // ---- P3: tanh tile (2 cols x 8 k per thread) ----
  {
    int pt = w >> 1, b = w & 1;
    float2 qq = *reinterpret_cast<const float2*>(&qv[w][2 * c2]);
    size_t bbase = (size_t)b * NN;
#pragma unroll
    for (int j = 0; j < 8; j++) {
      int k = kh * 8 + j;
      const ushort* krow = kg + (bbase + idx_s[pt][k]) * AA;
      unsigned ku = *reinterpret_cast<const unsigned*>(&krow[2 * c2]);
      unsigned ru = *reinterpret_cast<const unsigned*>(&ra_bs[pt * 16 + k][2 * c2]);
      float x0 = qq.x - bflo(ku) + bflo(ru);
      float x1 = qq.y - bfhi(ku) + bfhi(ru);
      float t0 = 1.f - 2.f * __builtin_amdgcn_rcpf(__expf(2.f * x0) + 1.f);
      float t1 = 1.f - 2.f * __builtin_amdgcn_rcpf(__expf(2.f * x1) + 1.f);
      astore2(A0, w * 16 + k, c2, t0, t1);
    }
  }
  __syncthreads();

  // ---- P4: score-hidden MFMA; relu * Ws2[col] -> hidp ----
  {
    bf16x8 fsA = loadfrag(pS, 16 + w, lane);
    bf16x8 fsB = loadfrag(pS, 20 + w, lane);
    int col = w * 16 + c16;
    float bsc = bs1[col], wsc = Ws2[col];
#pragma unroll
    for (int mt = 0; mt < 4; mt++) {
      bf16x8 a0 = afrag(A0, mt * 16, lane, 0), a1 = afrag(A0, mt * 16, lane, 1);
      f32x4 acc = {0.f, 0.f, 0.f, 0.f};
      acc = __builtin_amdgcn_mfma_f32_16x16x32_bf16(a0, fsA, acc, 0, 0, 0);
      acc = __builtin_amdgcn_mfma_f32_16x16x32_bf16(a1, fsB, acc, 0, 0, 0);
#pragma unroll
      for (int r = 0; r < 4; r++)
        hidp[mt * 16 + g * 4 + r][col] = fmaxf(acc[r] + bsc, 0.f) * wsc;
    }
  }
  __syncthreads();

  // ---- P5: row-sum + softmax over each 16-row group ----
  if (t < 64) {
    float s = 0.f;
#pragma unroll
    for (int c = 0; c < 16; c++) {
      float4 v4 = *reinterpret_cast<const float4*>(&hidp[t][c * 4]);
      s += v4.x + v4.y + v4.z + v4.w;
    }
    float sc = (s + bs2[0]) * 0.125f;
    float mx = sc;
#pragma unroll
    for (int o = 8; o > 0; o >>= 1) mx = fmaxf(mx, __shfl_xor(mx, o, 64));
    float e = __expf(sc - mx);
    float ss = e;
#pragma unroll
    for (int o = 8; o > 0; o >>= 1) ss += __shfl_xor(ss, o, 64);
    attn_s[t] = e / ss;
  }
  __syncthreads();

  // ---- P6: ctx = attn @ (vn + rv) (2 cols x 8 k + cross-half reduce) ----
  {
    int pt = w >> 1, b = w & 1;
    size_t bbase = (size_t)b * NN;
    float a0 = 0.f, a1 = 0.f;
#pragma unroll
    for (int j = 0; j < 8; j++) {
      int k = kh * 8 + j;
      const ushort* vrow = vg + (bbase + idx_s[pt][k]) * VV;
      unsigned vu = *reinterpret_cast<const unsigned*>(&vrow[2 * c2]);
      unsigned ru = *reinterpret_cast<const unsigned*>(&rv_bs[pt * 16 + k][2 * c2]);
      float aw = attn_s[w * 16 + k];
      a0 += aw * (bflo(vu) + bflo(ru));
      a1 += aw * (bfhi(vu) + bfhi(ru));
    }
    a0 += __shfl_xor(a0, 32, 64);
    a1 += __shfl_xor(a1, 32, 64);
    if (kh == 0) astore2(ctile, w, c2, a0, a1);
  }
  __syncthreads();

  // ---- P7: xmid = x + ctx @ Wo + bo (MFMA) ----
  {
    bf16x8 a0 = afrag(ctile, 0, lane, 0), a1 = afrag(ctile, 0, lane, 1);
    f32x4 acc[4];
#pragma unroll
    for (int j = 0; j < 4; j++) {
      bf16x8 b0 = loadfrag(pWo, 0 + w * 4 + j, lane);
      bf16x8 b1 = loadfrag(pWo, 16 + w * 4 + j, lane);
      f32x4 a = {0.f, 0.f, 0.f, 0.f};
      a = __builtin_amdgcn_mfma_f32_16x16x32_bf16(a0, b0, a, 0, 0, 0);
      a = __builtin_amdgcn_mfma_f32_16x16x32_bf16(a1, b1, a, 0, 0, 0);
      acc[j] = a;
    }
    if (g == 0) {
#pragma unroll
      for (int j = 0; j < 4; j++) {
        int col = w * 64 + j * 16 + c16;
        float bb = bo[col];
#pragma unroll
        for (int r = 0; r < 4; r++) {   // r = mt = pt*2+b
          int pt = r >> 1, b = r & 1;
          size_t addr = ((size_t)b * NN + n0 + pt) * DD + col;
          xmid[addr] = x[addr] + acc[j][r] + bb;
        }
      }
    }
  }
}

// ---------------- Kernel 3: LN2 + FFN + residual (MFMA, prefetched) ----------------
__global__ __launch_bounds__(256) void k_ffn(
    const float* __restrict__ xmid, const float* __restrict__ g2, const float* __restrict__ b2,
    const ushort* __restrict__ pWf1, const float* __restrict__ bf1,
    const ushort* __restrict__ pWf2, const float* __restrict__ bf2,
    float* __restrict__ out) {
  __shared__ __align__(16) ushort hs[32 * 256];
  __shared__ __align__(16) ushort ys[32 * 512];
  int t = threadIdx.x, lane = t & 63, w = t >> 6;
  size_t row0 = (size_t)blockIdx.x * 32;
  int rowa = lane & 15, gg = lane >> 4;

  {
    const float4 gv = *reinterpret_cast<const float4*>(&g2[lane * 4]);
    const float4 bvv = *reinterpret_cast<const float4*>(&b2[lane * 4]);
#pragma unroll
    for (int r8 = 0; r8 < 8; r8++) {
      int r = w * 8 + r8;
      const float4 xv = *reinterpret_cast<const float4*>(&xmid[(row0 + r) * DD + lane * 4]);
      float s = xv.x + xv.y + xv.z + xv.w;
      float s2 = xv.x * xv.x + xv.y * xv.y + xv.z * xv.z + xv.w * xv.w;
      for (int o = 32; o > 0; o >>= 1) { s += __shfl_down(s, o, 64); s2 += __shfl_down(s2, o, 64); }
      s = __shfl(s, 0, 64); s2 = __shfl(s2, 0, 64);
      float m = s * (1.f / DD), rs = rsqrtf(s2 * (1.f / DD) - m * m + 1e-5f);
      u16x4 hv;
      hv[0] = f2bf((xv.x - m) * rs * gv.x + bvv.x);
      hv[1] = f2bf((xv.y - m) * rs * gv.y + bvv.y);
      hv[2] = f2bf((xv.z - m) * rs * gv.z + bvv.z);
      hv[3] = f2bf((xv.w - m) * rs * gv.w + bvv.w);
      int off = (r * 512 + lane * 8) ^ ((r & 7) << 4);
      *reinterpret_cast<u16x4*>(reinterpret_cast<char*>(hs) + off) = hv;
    }
  }
  __syncthreads();

  // GEMM1: depth-1 double-buffered weight prefetch (fA/fB)
  f32x4 acc1[2][8] = {};
  {
    bf16x8 fA[8], fB[8];
#pragma unroll
    for (int j = 0; j < 8; j++) fA[j] = loadfrag(pWf1, w * 8 + j, lane);
#pragma unroll
    for (int ks = 0; ks < 8; ks += 2) {
#pragma unroll
      for (int j = 0; j < 8; j++) fB[j] = loadfrag(pWf1, (ks + 1) * 32 + w * 8 + j, lane);
      {
        bf16x8 a0 = *reinterpret_cast<const bf16x8*>(reinterpret_cast<const char*>(hs) +
                     ((rowa * 512 + ks * 64 + gg * 16) ^ ((rowa & 7) << 4)));
        bf16x8 a1 = *reinterpret_cast<const bf16x8*>(reinterpret_cast<const char*>(hs) +
                     (((rowa + 16) * 512 + ks * 64 + gg * 16) ^ ((rowa & 7) << 4)));
#pragma unroll
        for (int j = 0; j < 8; j++) {
          acc1[0][j] = __builtin_amdgcn_mfma_f32_16x16x32_bf16(a0, fA[j], acc1[0][j], 0, 0, 0);
          acc1[1][j] = __builtin_amdgcn_mfma_f32_16x16x32_bf16(a1, fA[j], acc1[1][j], 0, 0, 0);
        }
      }
      if (ks + 2 < 8) {
#pragma unroll
        for (int j = 0; j < 8; j++) fA[j] = loadfrag(pWf1, (ks + 2) * 32 + w * 8 + j, lane);
      }
      {
        bf16x8 a0 = *reinterpret_cast<const bf16x8*>(reinterpret_cast<const char*>(hs) +
                     ((rowa * 512 + (ks + 1) * 64 + gg * 16) ^ ((rowa & 7) << 4)));
        bf16x8 a1 = *reinterpret_cast<const bf16x8*>(reinterpret_cast<const char*>(hs) +
                     (((rowa + 16) * 512 + (ks + 1) * 64 + gg * 16) ^ ((rowa & 7) << 4)));
#pragma unroll
        for (int j = 0; j < 8; j++) {
          acc1[0][j] = __builtin_amdgcn_mfma_f32_16x16x32_bf16(a0, fB[j], acc1[0][j], 0, 0, 0);
          acc1[1][j] = __builtin_amdgcn_mfma_f32_16x16x32_bf16(a1, fB[j], acc1[1][j], 0, 0, 0);
        }
      }
    }
  }

#pragma unroll
  for (int j = 0; j < 8; j++) {
    int col = w * 128 + j * 16 + (lane & 15);
    float bb = bf1[col];
#pragma unroll
    for (int mt = 0; mt < 2; mt++)
#pragma unroll
      for (int r = 0; r < 4; r++) {
        float v = acc1[mt][j][r] + bb;
        v = v * 0.5f * (1.f + erff(v * 0.70710678118654752f));
        int row = mt * 16 + (lane >> 4) * 4 + r;
        int off = (row * 1024 + col * 2) ^ ((row & 7) << 4);
        *reinterpret_cast<ushort*>(reinterpret_cast<char*>(ys) + off) = f2bf(v);
      }
  }
  __syncthreads();

  // GEMM2: depth-2 rotating weight prefetch (fully unrolled -> static indices)
  f32x4 acc2[2][4] = {};
  {
    bf16x8 f2[3][4];
#pragma unroll
    for (int p = 0; p < 2; p++)
#pragma unroll
      for (int j = 0; j < 4; j++) f2[p][j] = loadfrag(pWf2, p * 16 + w * 4 + j, lane);
#pragma unroll
    for (int ks = 0; ks < 16; ks++) {
      if (ks + 2 < 16) {
#pragma unroll
        for (int j = 0; j < 4; j++) f2[(ks + 2) % 3][j] = loadfrag(pWf2, (ks + 2) * 16 + w * 4 + j, lane);
      }
      bf16x8 a0 = *reinterpret_cast<const bf16x8*>(reinterpret_cast<const char*>(ys) +
                   ((rowa * 1024 + ks * 64 + gg * 16) ^ ((rowa & 7) << 4)));
      bf16x8 a1 = *reinterpret_cast<const bf16x8*>(reinterpret_cast<const char*>(ys) +
                   (((rowa + 16) * 1024 + ks * 64 + gg * 16) ^ ((rowa & 7) << 4)));
#pragma unroll
      for (int j = 0; j < 4; j++) {
        acc2[0][j] = __builtin_amdgcn_mfma_f32_16x16x32_bf16(a0, f2[ks % 3][j], acc2[0][j], 0, 0, 0);
        acc2[1][j] = __builtin_amdgcn_mfma_f32_16x16x32_bf16(a1, f2[ks % 3][j], acc2[1][j], 0, 0, 0);
      }
    }
  }

#pragma unroll
  for (int j = 0; j < 4; j++) {
    int col = w * 64 + j * 16 + (lane & 15);
    float bb = bf2[col];
#pragma unroll
    for (int mt = 0; mt < 2; mt++)
#pragma unroll
      for (int r = 0; r < 4; r++) {
        int row = mt * 16 + (lane >> 4) * 4 + r;
        size_t idx = (row0 + row) * DD + col;
        out[idx] = xmid[idx] + acc2[mt][j][r] + bb;
      }
  }
}

extern "C" void kernel_launch(void* const* d_in, const int* in_sizes, int n_in,
                              void* d_out, int out_size, void* d_ws, size_t ws_size,
                              hipStream_t stream) {
  const float* x      = (const float*)d_in[0];
  const int*   knn    = (const int*)  d_in[1];
  const float* relpos = (const float*)d_in[2];
  const float* g1     = (const float*)d_in[3];
  const float* b1     = (const float*)d_in[4];
  const float* g2     = (const float*)d_in[5];
  const float* b2     = (const float*)d_in[6];
  const float* Wq     = (const float*)d_in[7];
  const float* bq     = (const float*)d_in[8];
  const float* Wk     = (const float*)d_in[9];
  const float* bk     = (const float*)d_in[10];
  const float* Wv     = (const float*)d_in[11];
  const float* bv     = (const float*)d_in[12];
  const float* Wo     = (const float*)d_in[13];
  const float* bo     = (const float*)d_in[14];
  const float* Wpa1   = (const float*)d_in[15];
  const float* bpa1   = (const float*)d_in[16];
  const float* Wpa2   = (const float*)d_in[17];
  const float* bpa2   = (const float*)d_in[18];
  const float* Wpv1   = (const float*)d_in[19];
  const float* bpv1   = (const float*)d_in[20];
  const float* Wpv2   = (const float*)d_in[21];
  const float* bpv2   = (const float*)d_in[22];
  const float* Ws1    = (const float*)d_in[23];
  const float* bs1    = (const float*)d_in[24];
  const float* Ws2    = (const float*)d_in[25];
  const float* bs2    = (const float*)d_in[26];
  const float* Wf1    = (const float*)d_in[27];
  const float* bf1    = (const float*)d_in[28];
  const float* Wf2    = (const float*)d_in[29];
  const float* bf2    = (const float*)d_in[30];

  ushort* qb = (ushort*)d_ws;                       // 3 x 8MB bf16 q/k/v
  ushort* kb = qb + (size_t)BB * NN * AA;
  ushort* vb = kb + (size_t)BB * NN * AA;
  float* xmid = (float*)(vb + (size_t)BB * NN * VV);
  ushort* pQKV = (ushort*)(xmid + (size_t)BB * NN * DD);
  ushort* pWf1 = pQKV + 49152;
  ushort* pWf2 = pWf1 + 131072;
  ushort* pS   = pWf2 + 131072;
  ushort* pWo  = pS + 12288;

  k_prep<<<166, 256, 0, stream>>>(Wq, Wk, Wv, Wf1, Wf2, Wpa2, Wpv2, Ws1, Wo,
                                  pQKV, pWf1, pWf2, pS, pWo);
  k_qkv<<<(BB * NN) / 32, 256, 0, stream>>>(x, g1, b1, pQKV, bq, bk, bv, qb, kb, vb);
  k_attn<<<NN / 2, 256, 0, stream>>>(x, relpos, knn, qb, kb, vb,
                                     Wpa1, bpa1, bpa2, Wpv1, bpv1, bpv2,
                                     pS, bs1, Ws2, bs2, pWo, bo, xmid);
  k_ffn<<<(BB * NN) / 32, 256, 0, stream>>>(xmid, g2, b2, pWf1, bf1, pWf2, bf2, (float*)d_out);
}

// Round 8
// 420.104 us; speedup vs baseline: 4.6765x; 1.0077x over previous
//
#include <hip/hip_runtime.h>
#include <hip/hip_bf16.h>
#include <math.h>

#define BB 2
#define NN 32768
#define KK 16
#define DD 256
#define AA 64
#define VV 64

typedef __attribute__((ext_vector_type(8))) short bf16x8;
typedef __attribute__((ext_vector_type(4))) float f32x4;
typedef __attribute__((ext_vector_type(4))) unsigned short u16x4;

__device__ __forceinline__ ushort f2bf(float v) {
  __hip_bfloat16 b = __float2bfloat16(v);
  ushort u; __builtin_memcpy(&u, &b, 2);
  return u;
}
__device__ __forceinline__ float bflo(unsigned u) { return __uint_as_float(u << 16); }
__device__ __forceinline__ float bfhi(unsigned u) { return __uint_as_float(u & 0xffff0000u); }

// swizzled bf16 tile helpers (row stride 128B, XOR swizzle (row&7)<<4)
__device__ __forceinline__ void astore(ushort* A, int row, int col, float v) {
  int off = (row * 128 + col * 2) ^ ((row & 7) << 4);
  *reinterpret_cast<ushort*>(reinterpret_cast<char*>(A) + off) = f2bf(v);
}
__device__ __forceinline__ void astore2(ushort* A, int row, int colpair, float lo, float hi) {
  int off = (row * 128 + colpair * 4) ^ ((row & 7) << 4);
  unsigned u = ((unsigned)f2bf(hi) << 16) | (unsigned)f2bf(lo);
  *reinterpret_cast<unsigned*>(reinterpret_cast<char*>(A) + off) = u;
}
__device__ __forceinline__ bf16x8 afrag(const ushort* A, int rowbase, int lane, int ks) {
  int row = rowbase + (lane & 15), g = lane >> 4;
  int off = (row * 128 + ks * 64 + g * 16) ^ ((row & 7) << 4);
  return *reinterpret_cast<const bf16x8*>(reinterpret_cast<const char*>(A) + off);
}
__device__ __forceinline__ bf16x8 loadfrag(const ushort* p, int fi, int lane) {
  return *reinterpret_cast<const bf16x8*>(&p[((size_t)fi * 64 + lane) * 8]);
}

// ---------------- Kernel 0: pack weights into bf16 B-fragment order ----------------
__global__ __launch_bounds__(256) void k_prep(
    const float* __restrict__ Wq, const float* __restrict__ Wk, const float* __restrict__ Wv,
    const float* __restrict__ Wf1, const float* __restrict__ Wf2,
    const float* __restrict__ Wpa2, const float* __restrict__ Wpv2,
    const float* __restrict__ Ws1, const float* __restrict__ Wo,
    const float* __restrict__ Wpa1, const float* __restrict__ Wpv1,
    ushort* __restrict__ pQKV, ushort* __restrict__ pWf1, ushort* __restrict__ pWf2,
    ushort* __restrict__ pS, ushort* __restrict__ pWo) {
  int tid = blockIdx.x * 256 + threadIdx.x;
  int lane = tid & 63, g = lane >> 4, c16 = lane & 15;
  bf16x8 f;
  if (tid < 6144) {                       // QKV: 8 ks x 12 nt
    int fi = tid >> 6; int ks = fi / 12, nt = fi % 12;
    int col = nt * 16 + c16;
    const float* W = (col < 64) ? Wq : (col < 128) ? Wk : Wv;
    int c = col & 63;
#pragma unroll
    for (int e = 0; e < 8; e++) f[e] = (short)f2bf(W[(ks * 32 + g * 8 + e) * 64 + c]);
    *reinterpret_cast<bf16x8*>(&pQKV[(size_t)tid * 8]) = f;
  } else if (tid < 22528) {               // Wf1: 8 ks x 32 nt
    int t2 = tid - 6144; int fi = t2 >> 6; int ks = fi >> 5, nt = fi & 31;
    int col = nt * 16 + c16;
#pragma unroll
    for (int e = 0; e < 8; e++) f[e] = (short)f2bf(Wf1[(ks * 32 + g * 8 + e) * 512 + col]);
    *reinterpret_cast<bf16x8*>(&pWf1[(size_t)t2 * 8]) = f;
  } else if (tid < 38912) {               // Wf2: 16 ks x 16 nt
    int t3 = tid - 22528; int fi = t3 >> 6; int ks = fi >> 4, nt = fi & 15;
    int col = nt * 16 + c16;
#pragma unroll
    for (int e = 0; e < 8; e++) f[e] = (short)f2bf(Wf2[(ks * 32 + g * 8 + e) * 256 + col]);
    *reinterpret_cast<bf16x8*>(&pWf2[(size_t)t3 * 8]) = f;
  } else if (tid < 40960) {               // pS: {Wpa2,Wpv2,Ws1} x 2ks x 4nt + K-padded {Wpa1,Wpv1} x 4nt
    int t4 = tid - 38912; int fi = t4 >> 6;
    if (fi < 24) {
      int mat = fi >> 3, ks = (fi >> 2) & 1, nt = fi & 3;
      const float* W = (mat == 0) ? Wpa2 : (mat == 1) ? Wpv2 : Ws1;
      int col = nt * 16 + c16;
#pragma unroll
      for (int e = 0; e < 8; e++) f[e] = (short)f2bf(W[(ks * 32 + g * 8 + e) * 64 + col]);
    } else {
      int mat = (fi - 24) >> 2, nt = fi & 3;
      const float* W = mat ? Wpv1 : Wpa1;
      int col = nt * 16 + c16;
#pragma unroll
      for (int e = 0; e < 8; e++) {
        int K = g * 8 + e;
        f[e] = (K < 3) ? (short)f2bf(W[K * 64 + col]) : (short)0;
      }
    }
    *reinterpret_cast<bf16x8*>(&pS[(size_t)t4 * 8]) = f;
  } else if (tid < 43008) {               // pWo: 2 ks x 16 nt
    int t5 = tid - 40960; int fi = t5 >> 6; int ks = fi >> 4, nt = fi & 15;
    int col = nt * 16 + c16;
#pragma unroll
    for (int e = 0; e < 8; e++) f[e] = (short)f2bf(Wo[(ks * 32 + g * 8 + e) * 256 + col]);
    *reinterpret_cast<bf16x8*>(&pWo[(size_t)t5 * 8]) = f;
  }
}

// ---------------- Kernel 1: LN1 + QKV projection (MFMA, bf16 outputs, prefetched) ----------------
__global__ __launch_bounds__(256) void k_qkv(
    const float* __restrict__ x, const float* __restrict__ g1, const float* __restrict__ b1,
    const ushort* __restrict__ pW,
    const float* __restrict__ bq, const float* __restrict__ bk, const float* __restrict__ bv,
    ushort* __restrict__ qo, ushort* __restrict__ ko, ushort* __restrict__ vo) {
  __shared__ __align__(16) ushort hs[32 * 256];
  int t = threadIdx.x, lane = t & 63, w = t >> 6;
  size_t row0 = (size_t)blockIdx.x * 32;

  {
    const float4 gv = *reinterpret_cast<const float4*>(&g1[lane * 4]);
    const float4 bvv = *reinterpret_cast<const float4*>(&b1[lane * 4]);
#pragma unroll
    for (int r8 = 0; r8 < 8; r8++) {
      int r = w * 8 + r8;
      const float4 xv = *reinterpret_cast<const float4*>(&x[(row0 + r) * DD + lane * 4]);
      float s = xv.x + xv.y + xv.z + xv.w;
      float s2 = xv.x * xv.x + xv.y * xv.y + xv.z * xv.z + xv.w * xv.w;
      for (int o = 32; o > 0; o >>= 1) { s += __shfl_down(s, o, 64); s2 += __shfl_down(s2, o, 64); }
      s = __shfl(s, 0, 64); s2 = __shfl(s2, 0, 64);
      float m = s * (1.f / DD), rs = rsqrtf(s2 * (1.f / DD) - m * m + 1e-5f);
      u16x4 hv;
      hv[0] = f2bf((xv.x - m) * rs * gv.x + bvv.x);
      hv[1] = f2bf((xv.y - m) * rs * gv.y + bvv.y);
      hv[2] = f2bf((xv.z - m) * rs * gv.z + bvv.z);
      hv[3] = f2bf((xv.w - m) * rs * gv.w + bvv.w);
      int off = (r * 512 + lane * 8) ^ ((r & 7) << 4);
      *reinterpret_cast<u16x4*>(reinterpret_cast<char*>(hs) + off) = hv;
    }
  }
  __syncthreads();

  f32x4 acc[2][3] = {};
  bf16x8 fw[3][3];
  int rowa = lane & 15, gg = lane >> 4;
#pragma unroll
  for (int p = 0; p < 2; p++)
#pragma unroll
    for (int j = 0; j < 3; j++) fw[p][j] = loadfrag(pW, p * 12 + w * 3 + j, lane);
#pragma unroll
  for (int ks = 0; ks < 8; ks++) {
    if (ks + 2 < 8) {
#pragma unroll
      for (int j = 0; j < 3; j++) fw[(ks + 2) % 3][j] = loadfrag(pW, (ks + 2) * 12 + w * 3 + j, lane);
    }
    bf16x8 a0 = *reinterpret_cast<const bf16x8*>(reinterpret_cast<const char*>(hs) +
                 ((rowa * 512 + ks * 64 + gg * 16) ^ ((rowa & 7) << 4)));
    bf16x8 a1 = *reinterpret_cast<const bf16x8*>(reinterpret_cast<const char*>(hs) +
                 (((rowa + 16) * 512 + ks * 64 + gg * 16) ^ ((rowa & 7) << 4)));
#pragma unroll
    for (int j = 0; j < 3; j++) {
      acc[0][j] = __builtin_amdgcn_mfma_f32_16x16x32_bf16(a0, fw[ks % 3][j], acc[0][j], 0, 0, 0);
      acc[1][j] = __builtin_amdgcn_mfma_f32_16x16x32_bf16(a1, fw[ks % 3][j], acc[1][j], 0, 0, 0);
    }
  }

#pragma unroll
  for (int j = 0; j < 3; j++) {
    int ntg = w * 3 + j;
    int buf = ntg >> 2;
    ushort* out = (buf == 0) ? qo : (buf == 1) ? ko : vo;
    const float* bias = (buf == 0) ? bq : (buf == 1) ? bk : bv;
    int col = (ntg & 3) * 16 + (lane & 15);
    float bb = bias[col];
#pragma unroll
    for (int mt = 0; mt < 2; mt++)
#pragma unroll
      for (int r = 0; r < 4; r++) {
        int row = mt * 16 + (lane >> 4) * 4 + r;
        out[(row0 + row) * 64 + col] = f2bf(acc[mt][j][r] + bb);
      }
  }
}

// ---------------- Kernel 2: attention, 2 points/block, batches fused ----------------
__global__ __launch_bounds__(256) void k_attn(
    const float* __restrict__ x, const float* __restrict__ relpos, const int* __restrict__ knn,
    const ushort* __restrict__ qg, const ushort* __restrict__ kg, const ushort* __restrict__ vg,
    const float* __restrict__ bpa1, const float* __restrict__ bpa2,
    const float* __restrict__ bpv1, const float* __restrict__ bpv2,
    const ushort* __restrict__ pS, const float* __restrict__ bs1,
    const float* __restrict__ Ws2, const float* __restrict__ bs2,
    const ushort* __restrict__ pWo, const float* __restrict__ bo,
    float* __restrict__ xmid) {
  int n0 = blockIdx.x * 2;
  int t = threadIdx.x, lane = t & 63, w = t >> 6;
  int g = lane >> 4, c16 = lane & 15;
  int c2 = lane & 31, kh = lane >> 5;   // column-pair / k-half decomposition

  __shared__ __align__(16) ushort A0[64 * 64];      // 8KB swizzled bf16 tile
  __shared__ __align__(16) ushort ra_bs[32][72];    // 4.5KB bf16
  __shared__ __align__(16) ushort rv_bs[32][72];    // 4.5KB bf16
  __shared__ __align__(16) ushort hid_bs[64][72];   // 9KB bf16 score partials
  __shared__ __align__(16) ushort RP[32 * 32];      // 2KB K-padded relpos (rows=pt*16+k, K 0..2=rp)
  __shared__ __align__(16) ushort ctile[16 * 64];   // 2KB
  __shared__ __align__(8) float qv[4][64];
  __shared__ float attn_s[64];
  __shared__ int idx_s[2][16];

  // ---- P0: idx, RP staging, q load ----
  if (t < 32) {
    idx_s[t >> 4][t & 15] = knn[(n0 + (t >> 4)) * KK + (t & 15)];
    float r0 = relpos[(size_t)n0 * 48 + t * 3 + 0];
    float r1 = relpos[(size_t)n0 * 48 + t * 3 + 1];
    float r2 = relpos[(size_t)n0 * 48 + t * 3 + 2];
    uint4 z; z.x = 0; z.y = 0; z.z = 0; z.w = 0;
    uint4 f0;
    f0.x = ((unsigned)f2bf(r1) << 16) | (unsigned)f2bf(r0);
    f0.y = (unsigned)f2bf(r2);
    f0.z = 0; f0.w = 0;
    *reinterpret_cast<uint4*>(&RP[t * 32 + 0])  = f0;
    *reinterpret_cast<uint4*>(&RP[t * 32 + 8])  = z;
    *reinterpret_cast<uint4*>(&RP[t * 32 + 16]) = z;
    *reinterpret_cast<uint4*>(&RP[t * 32 + 24]) = z;
  }
  qv[w][lane] = bflo(qg[((size_t)(w & 1) * NN + n0 + (w >> 1)) * AA + lane]);
  __syncthreads();

  // ---- P1: rel-pos MLP hidden via K-padded MFMA -> A0 ----
  {
    bf16x8 aRP0 = *reinterpret_cast<const bf16x8*>(&RP[(lane & 15) * 32 + g * 8]);         // pt0
    bf16x8 aRP1 = *reinterpret_cast<const bf16x8*>(&RP[((lane & 15) + 16) * 32 + g * 8]);  // pt1
    bf16x8 bA = loadfrag(pS, 24 + w, lane);
    bf16x8 bV = loadfrag(pS, 28 + w, lane);
    int col = w * 16 + c16;
    float ba = bpa1[col], bv1_ = bpv1[col];
    f32x4 zz = {0.f, 0.f, 0.f, 0.f};
    f32x4 hA0 = __builtin_amdgcn_mfma_f32_16x16x32_bf16(aRP0, bA, zz, 0, 0, 0);
    f32x4 hA1 = __builtin_amdgcn_mfma_f32_16x16x32_bf16(aRP1, bA, zz, 0, 0, 0);
    f32x4 hV0 = __builtin_amdgcn_mfma_f32_16x16x32_bf16(aRP0, bV, zz, 0, 0, 0);
    f32x4 hV1 = __builtin_amdgcn_mfma_f32_16x16x32_bf16(aRP1, bV, zz, 0, 0, 0);
#pragma unroll
    for (int r = 0; r < 4; r++) {
      astore(A0, 0  + g * 4 + r, col, fmaxf(hA0[r] + ba, 0.f));
      astore(A0, 16 + g * 4 + r, col, fmaxf(hA1[r] + ba, 0.f));
      astore(A0, 32 + g * 4 + r, col, fmaxf(hV0[r] + bv1_, 0.f));
      astore(A0, 48 + g * 4 + r, col, fmaxf(hV1[r] + bv1_, 0.f));
    }
  }

  // pre-issue P3's k-gathers (consumed two barriers later)
  unsigned kuval[8];
  {
    int pt3 = w >> 1, b3 = w & 1;
    size_t bbase = (size_t)b3 * NN;
#pragma unroll
    for (int j = 0; j < 8; j++) {
      int k = kh * 8 + j;
      kuval[j] = *reinterpret_cast<const unsigned*>(&kg[(bbase + idx_s[pt3][k]) * AA + 2 * c2]);
    }
  }
  __syncthreads();

  // ---- P2: ra/rv = hidden @ {Wpa2,Wpv2} + bias (MFMA) -> bf16 LDS ----
  {
    bf16x8 bwa0 = loadfrag(pS, 0 + w, lane);
    bf16x8 bwa1 = loadfrag(pS, 4 + w, lane);
    bf16x8 bwv0 = loadfrag(pS, 8 + w, lane);
    bf16x8 bwv1 = loadfrag(pS, 12 + w, lane);
    int col = w * 16 + c16;
    float ba2 = bpa2[col], bv2 = bpv2[col];
#pragma unroll
    for (int mt = 0; mt < 2; mt++) {
      bf16x8 a0 = afrag(A0, mt * 16, lane, 0), a1 = afrag(A0, mt * 16, lane, 1);
      f32x4 acc = {0.f, 0.f, 0.f, 0.f};
      acc = __builtin_amdgcn_mfma_f32_16x16x32_bf16(a0, bwa0, acc, 0, 0, 0);
      acc = __builtin_amdgcn_mfma_f32_16x16x32_bf16(a1, bwa1, acc, 0, 0, 0);
#pragma unroll
      for (int r = 0; r < 4; r++) ra_bs[mt * 16 + g * 4 + r][col] = f2bf(acc[r] + ba2);
      bf16x8 v0 = afrag(A0, 32 + mt * 16, lane, 0), v1 = afrag(A0, 32 + mt * 16, lane, 1);
      f32x4 accv = {0.f, 0.f, 0.f, 0.f};
      accv = __builtin_amdgcn_mfma_f32_16x16x32_bf16(v0, bwv0, accv, 0, 0, 0);
      accv = __builtin_amdgcn_mfma_f32_16x16x32_bf16(v1, bwv1, accv, 0, 0, 0);
#pragma unroll
      for (int r = 0; r < 4; r++) rv_bs[mt * 16 + g * 4 + r][col] = f2bf(accv[r] + bv2);
    }
  }
  __syncthreads();

  // ---- P3: tanh tile (2 cols x 8 k per thread, gathers pre-issued) ----
  {
    int pt = w >> 1;
    float2 qq = *reinterpret_cast<const float2*>(&qv[w][2 * c2]);
#pragma unroll
    for (int j = 0; j < 8; j++) {
      int k = kh * 8 + j;
      unsigned ku = kuval[j];
      unsigned ru = *reinterpret_cast<const unsigned*>(&ra_bs[pt * 16 + k][2 * c2]);
      float x0 = qq.x - bflo(ku) + bflo(ru);
      float x1 = qq.y - bfhi(ku) + bfhi(ru);
      float t0 = 1.f - 2.f * __builtin_amdgcn_rcpf(__expf(2.f * x0) + 1.f);
      float t1 = 1.f - 2.f * __builtin_amdgcn_rcpf(__expf(2.f * x1) + 1.f);
      astore2(A0, w * 16 + k, c2, t0, t1);
    }
  }
  __syncthreads();

  // ---- P4: score-hidden MFMA; relu * Ws2[col] -> hid_bs (bf16) ----
  {
    bf16x8 fsA = loadfrag(pS, 16 + w, lane);
    bf16x8 fsB = loadfrag(pS, 20 + w, lane);
    int col = w * 16 + c16;
    float bsc = bs1[col], wsc = Ws2[col];
#pragma unroll
    for (int mt = 0; mt < 4; mt++) {
      bf16x8 a0 = afrag(A0, mt * 16, lane, 0), a1 = afrag(A0, mt * 16, lane, 1);
      f32x4 acc = {0.f, 0.f, 0.f, 0.f};
      acc = __builtin_amdgcn_mfma_f32_16x16x32_bf16(a0, fsA, acc, 0, 0, 0);
      acc = __builtin_amdgcn_mfma_f32_16x16x32_bf16(a1, fsB, acc, 0, 0, 0);
#pragma unroll
      for (int r = 0; r < 4; r++)
        hid_bs[mt * 16 + g * 4 + r][col] = f2bf(fmaxf(acc[r] + bsc, 0.f) * wsc);
    }
  }
  __syncthreads();

  // ---- P5: row-sum + softmax over each 16-row group ----
  if (t < 64) {
    const uint4* hrow = reinterpret_cast<const uint4*>(&hid_bs[t][0]);
    float s = 0.f;
#pragma unroll
    for (int c = 0; c < 8; c++) {
      uint4 v4 = hrow[c];
      s += bflo(v4.x) + bfhi(v4.x) + bflo(v4.y) + bfhi(v4.y) +
           bflo(v4.z) + bfhi(v4.z) + bflo(v4.w) + bfhi(v4.w);
    }
    float sc = (s + bs2[0]) * 0.125f;
    float mx = sc;
#pragma unroll
    for (int o = 8; o > 0; o >>= 1) mx = fmaxf(mx, __shfl_xor(mx, o, 64));
    float e = __expf(sc - mx);
    float ss = e;
#pragma unroll
    for (int o = 8; o > 0; o >>= 1) ss += __shfl_xor(ss, o, 64);
    attn_s[t] = e / ss;
  }
  __syncthreads();

  // ---- P6: ctx = attn @ (vn + rv) (2 cols x 8 k + cross-half reduce) ----
  {
    int pt = w >> 1, b = w & 1;
    size_t bbase = (size_t)b * NN;
    float a0 = 0.f, a1 = 0.f;
#pragma unroll
    for (int j = 0; j < 8; j++) {
      int k = kh * 8 + j;
      const ushort* vrow = vg + (bbase + idx_s[pt][k]) * VV;
      unsigned vu = *reinterpret_cast<const unsigned*>(&vrow[2 * c2]);
      unsigned ru = *reinterpret_cast<const unsigned*>(&rv_bs[pt * 16 + k][2 * c2]);
      float aw = attn_s[w * 16 + k];
      a0 += aw * (bflo(vu) + bflo(ru));
      a1 += aw * (bfhi(vu) + bfhi(ru));
    }
    a0 += __shfl_xor(a0, 32, 64);
    a1 += __shfl_xor(a1, 32, 64);
    if (kh == 0) astore2(ctile, w, c2, a0, a1);
  }
  __syncthreads();

  // ---- P7: xmid = x + ctx @ Wo + bo (MFMA; junk A-rows 4-15 only affect discarded D rows) ----
  {
    bf16x8 a0 = afrag(ctile, 0, lane, 0), a1 = afrag(ctile, 0, lane, 1);
    f32x4 acc[4];
#pragma unroll
    for (int j = 0; j < 4; j++) {
      bf16x8 b0 = loadfrag(pWo, 0 + w * 4 + j, lane);
      bf16x8 b1 = loadfrag(pWo, 16 + w * 4 + j, lane);
      f32x4 a = {0.f, 0.f, 0.f, 0.f};
      a = __builtin_amdgcn_mfma_f32_16x16x32_bf16(a0, b0, a, 0, 0, 0);
      a = __builtin_amdgcn_mfma_f32_16x16x32_bf16(a1, b1, a, 0, 0, 0);
      acc[j] = a;
    }
    if (g == 0) {
#pragma unroll
      for (int j = 0; j < 4; j++) {
        int col = w * 64 + j * 16 + c16;
        float bb = bo[col];
#pragma unroll
        for (int r = 0; r < 4; r++) {   // r = mt = pt*2+b
          int pt = r >> 1, b = r & 1;
          size_t addr = ((size_t)b * NN + n0 + pt) * DD + col;
          xmid[addr] = x[addr] + acc[j][r] + bb;
        }
      }
    }
  }
}

// ---------------- Kernel 3: LN2 + FFN + residual (MFMA, prefetched) ----------------
__global__ __launch_bounds__(256) void k_ffn(
    const float* __restrict__ xmid, const float* __restrict__ g2, const float* __restrict__ b2,
    const ushort* __restrict__ pWf1, const float* __restrict__ bf1,
    const ushort* __restrict__ pWf2, const float* __restrict__ bf2,
    float* __restrict__ out) {
  __shared__ __align__(16) ushort hs[32 * 256];
  __shared__ __align__(16) ushort ys[32 * 512];
  int t = threadIdx.x, lane = t & 63, w = t >> 6;
  size_t row0 = (size_t)blockIdx.x * 32;
  int rowa = lane & 15, gg = lane >> 4;

  {
    const float4 gv = *reinterpret_cast<const float4*>(&g2[lane * 4]);
    const float4 bvv = *reinterpret_cast<const float4*>(&b2[lane * 4]);
#pragma unroll
    for (int r8 = 0; r8 < 8; r8++) {
      int r = w * 8 + r8;
      const float4 xv = *reinterpret_cast<const float4*>(&xmid[(row0 + r) * DD + lane * 4]);
      float s = xv.x + xv.y + xv.z + xv.w;
      float s2 = xv.x * xv.x + xv.y * xv.y + xv.z * xv.z + xv.w * xv.w;
      for (int o = 32; o > 0; o >>= 1) { s += __shfl_down(s, o, 64); s2 += __shfl_down(s2, o, 64); }
      s = __shfl(s, 0, 64); s2 = __shfl(s2, 0, 64);
      float m = s * (1.f / DD), rs = rsqrtf(s2 * (1.f / DD) - m * m + 1e-5f);
      u16x4 hv;
      hv[0] = f2bf((xv.x - m) * rs * gv.x + bvv.x);
      hv[1] = f2bf((xv.y - m) * rs * gv.y + bvv.y);
      hv[2] = f2bf((xv.z - m) * rs * gv.z + bvv.z);
      hv[3] = f2bf((xv.w - m) * rs * gv.w + bvv.w);
      int off = (r * 512 + lane * 8) ^ ((r & 7) << 4);
      *reinterpret_cast<u16x4*>(reinterpret_cast<char*>(hs) + off) = hv;
    }
  }
  __syncthreads();

  // GEMM1: depth-1 double-buffered weight prefetch (fA/fB)
  f32x4 acc1[2][8] = {};
  {
    bf16x8 fA[8], fB[8];
#pragma unroll
    for (int j = 0; j < 8; j++) fA[j] = loadfrag(pWf1, w * 8 + j, lane);
#pragma unroll
    for (int ks = 0; ks < 8; ks += 2) {
#pragma unroll
      for (int j = 0; j < 8; j++) fB[j] = loadfrag(pWf1, (ks + 1) * 32 + w * 8 + j, lane);
      {
        bf16x8 a0 = *reinterpret_cast<const bf16x8*>(reinterpret_cast<const char*>(hs) +
                     ((rowa * 512 + ks * 64 + gg * 16) ^ ((rowa & 7) << 4)));
        bf16x8 a1 = *reinterpret_cast<const bf16x8*>(reinterpret_cast<const char*>(hs) +
                     (((rowa + 16) * 512 + ks * 64 + gg * 16) ^ ((rowa & 7) << 4)));
#pragma unroll
        for (int j = 0; j < 8; j++) {
          acc1[0][j] = __builtin_amdgcn_mfma_f32_16x16x32_bf16(a0, fA[j], acc1[0][j], 0, 0, 0);
          acc1[1][j] = __builtin_amdgcn_mfma_f32_16x16x32_bf16(a1, fA[j], acc1[1][j], 0, 0, 0);
        }
      }
      if (ks + 2 < 8) {
#pragma unroll
        for (int j = 0; j < 8; j++) fA[j] = loadfrag(pWf1, (ks + 2) * 32 + w * 8 + j, lane);
      }
      {
        bf16x8 a0 = *reinterpret_cast<const bf16x8*>(reinterpret_cast<const char*>(hs) +
                     ((rowa * 512 + (ks + 1) * 64 + gg * 16) ^ ((rowa & 7) << 4)));
        bf16x8 a1 = *reinterpret_cast<const bf16x8*>(reinterpret_cast<const char*>(hs) +
                     (((rowa + 16) * 512 + (ks + 1) * 64 + gg * 16) ^ ((rowa & 7) << 4)));
#pragma unroll
        for (int j = 0; j < 8; j++) {
          acc1[0][j] = __builtin_amdgcn_mfma_f32_16x16x32_bf16(a0, fB[j], acc1[0][j], 0, 0, 0);
          acc1[1][j] = __builtin_amdgcn_mfma_f32_16x16x32_bf16(a1, fB[j], acc1[1][j], 0, 0, 0);
        }
      }
    }
  }

#pragma unroll
  for (int j = 0; j < 8; j++) {
    int col = w * 128 + j * 16 + (lane & 15);
    float bb = bf1[col];
#pragma unroll
    for (int mt = 0; mt < 2; mt++)
#pragma unroll
      for (int r = 0; r < 4; r++) {
        float v = acc1[mt][j][r] + bb;
        v = v * 0.5f * (1.f + erff(v * 0.70710678118654752f));
        int row = mt * 16 + (lane >> 4) * 4 + r;
        int off = (row * 1024 + col * 2) ^ ((row & 7) << 4);
        *reinterpret_cast<ushort*>(reinterpret_cast<char*>(ys) + off) = f2bf(v);
      }
  }
  __syncthreads();

  // GEMM2: depth-2 rotating weight prefetch (fully unrolled -> static indices)
  f32x4 acc2[2][4] = {};
  {
    bf16x8 f2[3][4];
#pragma unroll
    for (int p = 0; p < 2; p++)
#pragma unroll
      for (int j = 0; j < 4; j++) f2[p][j] = loadfrag(pWf2, p * 16 + w * 4 + j, lane);
#pragma unroll
    for (int ks = 0; ks < 16; ks++) {
      if (ks + 2 < 16) {
#pragma unroll
        for (int j = 0; j < 4; j++) f2[(ks + 2) % 3][j] = loadfrag(pWf2, (ks + 2) * 16 + w * 4 + j, lane);
      }
      bf16x8 a0 = *reinterpret_cast<const bf16x8*>(reinterpret_cast<const char*>(ys) +
                   ((rowa * 1024 + ks * 64 + gg * 16) ^ ((rowa & 7) << 4)));
      bf16x8 a1 = *reinterpret_cast<const bf16x8*>(reinterpret_cast<const char*>(ys) +
                   (((rowa + 16) * 1024 + ks * 64 + gg * 16) ^ ((rowa & 7) << 4)));
#pragma unroll
      for (int j = 0; j < 4; j++) {
        acc2[0][j] = __builtin_amdgcn_mfma_f32_16x16x32_bf16(a0, f2[ks % 3][j], acc2[0][j], 0, 0, 0);
        acc2[1][j] = __builtin_amdgcn_mfma_f32_16x16x32_bf16(a1, f2[ks % 3][j], acc2[1][j], 0, 0, 0);
      }
    }
  }

#pragma unroll
  for (int j = 0; j < 4; j++) {
    int col = w * 64 + j * 16 + (lane & 15);
    float bb = bf2[col];
#pragma unroll
    for (int mt = 0; mt < 2; mt++)
#pragma unroll
      for (int r = 0; r < 4; r++) {
        int row = mt * 16 + (lane >> 4) * 4 + r;
        size_t idx = (row0 + row) * DD + col;
        out[idx] = xmid[idx] + acc2[mt][j][r] + bb;
      }
  }
}

extern "C" void kernel_launch(void* const* d_in, const int* in_sizes, int n_in,
                              void* d_out, int out_size, void* d_ws, size_t ws_size,
                              hipStream_t stream) {
  const float* x      = (const float*)d_in[0];
  const int*   knn    = (const int*)  d_in[1];
  const float* relpos = (const float*)d_in[2];
  const float* g1     = (const float*)d_in[3];
  const float* b1     = (const float*)d_in[4];
  const float* g2     = (const float*)d_in[5];
  const float* b2     = (const float*)d_in[6];
  const float* Wq     = (const float*)d_in[7];
  const float* bq     = (const float*)d_in[8];
  const float* Wk     = (const float*)d_in[9];
  const float* bk     = (const float*)d_in[10];
  const float* Wv     = (const float*)d_in[11];
  const float* bv     = (const float*)d_in[12];
  const float* Wo     = (const float*)d_in[13];
  const float* bo     = (const float*)d_in[14];
  const float* Wpa1   = (const float*)d_in[15];
  const float* bpa1   = (const float*)d_in[16];
  const float* Wpa2   = (const float*)d_in[17];
  const float* bpa2   = (const float*)d_in[18];
  const float* Wpv1   = (const float*)d_in[19];
  const float* bpv1   = (const float*)d_in[20];
  const float* Wpv2   = (const float*)d_in[21];
  const float* bpv2   = (const float*)d_in[22];
  const float* Ws1    = (const float*)d_in[23];
  const float* bs1    = (const float*)d_in[24];
  const float* Ws2    = (const float*)d_in[25];
  const float* bs2    = (const float*)d_in[26];
  const float* Wf1    = (const float*)d_in[27];
  const float* bf1    = (const float*)d_in[28];
  const float* Wf2    = (const float*)d_in[29];
  const float* bf2    = (const float*)d_in[30];

  ushort* qb = (ushort*)d_ws;                       // 3 x 8MB bf16 q/k/v
  ushort* kb = qb + (size_t)BB * NN * AA;
  ushort* vb = kb + (size_t)BB * NN * AA;
  float* xmid = (float*)(vb + (size_t)BB * NN * VV);
  ushort* pQKV = (ushort*)(xmid + (size_t)BB * NN * DD);
  ushort* pWf1 = pQKV + 49152;
  ushort* pWf2 = pWf1 + 131072;
  ushort* pS   = pWf2 + 131072;
  ushort* pWo  = pS + 16384;

  k_prep<<<168, 256, 0, stream>>>(Wq, Wk, Wv, Wf1, Wf2, Wpa2, Wpv2, Ws1, Wo, Wpa1, Wpv1,
                                  pQKV, pWf1, pWf2, pS, pWo);
  k_qkv<<<(BB * NN) / 32, 256, 0, stream>>>(x, g1, b1, pQKV, bq, bk, bv, qb, kb, vb);
  k_attn<<<NN / 2, 256, 0, stream>>>(x, relpos, knn, qb, kb, vb,
                                     bpa1, bpa2, bpv1, bpv2,
                                     pS, bs1, Ws2, bs2, pWo, bo, xmid);
  k_ffn<<<(BB * NN) / 32, 256, 0, stream>>>(xmid, g2, b2, pWf1, bf1, pWf2, bf2, (float*)d_out);
}